// Round 1
// baseline (827.558 us; speedup 1.0000x reference)
//
#include <hip/hip_runtime.h>

#define DM 1024
#define BATCH 4
#define SEQ 2048
#define M_TOT (BATCH*SEQ)

// ---------------- workspace layout (float offsets) ----------------
// qr   [B,DM]     @ 0
// kr   [B,DM]     @ 4096
// G    [2]        @ 8192   (G[0]=sum gqw, G[1]=sum gkw)
// gq   [B,DM]     @ 12288
// gk   [B,DM]     @ 16384
// Qs   [M,DM]     @ 32768          (Q projection * gqw[s])
// Vp   [M,DM]     @ 32768+M*DM     (V projection)
#define WS_QR 0
#define WS_KR 4096
#define WS_G  8192
#define WS_GQ 12288
#define WS_GK 16384
#define WS_QS 32768
#define WS_VP (32768 + (size_t)M_TOT*DM)

// K1: qr[b,:] = sum_s gqw[s]*q[b,s,:]; kr likewise; G = [sum gqw, sum gkw]
__global__ void k_reduce(const float* __restrict__ q, const float* __restrict__ k,
                         const float* __restrict__ gqw, const float* __restrict__ gkw,
                         float* __restrict__ qr, float* __restrict__ kr,
                         float* __restrict__ G) {
  const int b = blockIdx.x, dch = blockIdx.y, sch = blockIdx.z;
  const int d = dch * 256 + threadIdx.x;
  const int s0 = sch * (SEQ / 16);
  const float* qp = q + ((size_t)b * SEQ + s0) * DM + d;
  const float* kp = k + ((size_t)b * SEQ + s0) * DM + d;
  float aq = 0.f, ak = 0.f;
  for (int i = 0; i < SEQ / 16; ++i) {
    aq += gqw[s0 + i] * qp[(size_t)i * DM];
    ak += gkw[s0 + i] * kp[(size_t)i * DM];
  }
  atomicAdd(&qr[b * DM + d], aq);
  atomicAdd(&kr[b * DM + d], ak);
  if (b == 0 && dch == 0 && threadIdx.x < SEQ / 16) {
    atomicAdd(&G[0], gqw[s0 + threadIdx.x]);
    atomicAdd(&G[1], gkw[s0 + threadIdx.x]);
  }
}

// K2: gq[b,d] = qr[b,:]@wq[:,d] + bq[d]*G0 ; gk[b,d] = gq * (kr[b,:]@wk[:,d] + bk[d]*G1)
__global__ void k_globalvec(const float* __restrict__ wq, const float* __restrict__ bq,
                            const float* __restrict__ wk, const float* __restrict__ bk,
                            const float* __restrict__ qr, const float* __restrict__ kr,
                            const float* __restrict__ G,
                            float* __restrict__ gq, float* __restrict__ gk) {
  const int b = blockIdx.x;
  const int d = blockIdx.y * 256 + threadIdx.x;
  __shared__ float sqr[DM], skr[DM];
  for (int i = threadIdx.x; i < DM; i += 256) {
    sqr[i] = qr[b * DM + i];
    skr[i] = kr[b * DM + i];
  }
  __syncthreads();
  float accq = 0.f, acck = 0.f;
  for (int kk = 0; kk < DM; ++kk) {
    accq += sqr[kk] * wq[(size_t)kk * DM + d];
    acck += skr[kk] * wk[(size_t)kk * DM + d];
  }
  const float gqv = accq + bq[d] * G[0];
  const float gkr = acck + bk[d] * G[1];
  gq[b * DM + d] = gqv;
  gk[b * DM + d] = gqv * gkr;
}

// K3: out[m,n] = (A[m,:]@W[:,n] + bias[n]) * (SCALE ? rowscale[m % SEQ] : 1)
// 64x64 tile, BK=16, 256 threads, 4x4 micro-tile.
template <bool SCALE>
__global__ void k_proj(const float* __restrict__ A, const float* __restrict__ W,
                       const float* __restrict__ bias, const float* __restrict__ rowscale,
                       float* __restrict__ out) {
  __shared__ __align__(16) float As[16][68];  // [kk][row], pad 68 -> 2-way max
  __shared__ __align__(16) float Ws[16][64];  // [kk][col]
  const int m0 = blockIdx.x * 64, n0 = blockIdx.y * 64;
  const int tid = threadIdx.x;
  const int ty = tid >> 4, tx = tid & 15;
  float c[4][4] = {};
  for (int k0 = 0; k0 < DM; k0 += 16) {
#pragma unroll
    for (int p = 0; p < 4; ++p) {
      int e = tid + p * 256;
      int row = e >> 4, kk = e & 15;
      As[kk][row] = A[(size_t)(m0 + row) * DM + k0 + kk];
    }
#pragma unroll
    for (int p = 0; p < 4; ++p) {
      int e = tid + p * 256;
      int kk = e >> 6, col = e & 63;
      Ws[kk][col] = W[(size_t)(k0 + kk) * DM + n0 + col];
    }
    __syncthreads();
#pragma unroll
    for (int kk = 0; kk < 16; ++kk) {
      float4 av = *reinterpret_cast<const float4*>(&As[kk][ty * 4]);
      float4 bv = *reinterpret_cast<const float4*>(&Ws[kk][tx * 4]);
      float a[4] = {av.x, av.y, av.z, av.w};
      float bb[4] = {bv.x, bv.y, bv.z, bv.w};
#pragma unroll
      for (int i = 0; i < 4; ++i)
#pragma unroll
        for (int j = 0; j < 4; ++j) c[i][j] += a[i] * bb[j];
    }
    __syncthreads();
  }
#pragma unroll
  for (int i = 0; i < 4; ++i) {
    const int r = m0 + ty * 4 + i;
    const float sc = SCALE ? rowscale[r & (SEQ - 1)] : 1.0f;
#pragma unroll
    for (int j = 0; j < 4; ++j) {
      const int n = n0 + tx * 4 + j;
      out[(size_t)r * DM + n] = (c[i][j] + bias[n]) * sc;
    }
  }
}

// K4: OUT[m,n] = ((Vp*gk + Qs)[m,:] @ wo[:,n]) + bo[n]
__global__ void k_out(const float* __restrict__ Vp, const float* __restrict__ Qs,
                      const float* __restrict__ gk, const float* __restrict__ wo,
                      const float* __restrict__ bo, float* __restrict__ out) {
  __shared__ __align__(16) float As[16][68];
  __shared__ __align__(16) float Ws[16][64];
  const int m0 = blockIdx.x * 64, n0 = blockIdx.y * 64;
  const int b = m0 >> 11;  // m0 / SEQ (tiles never straddle batches: 2048 % 64 == 0)
  const int tid = threadIdx.x;
  const int ty = tid >> 4, tx = tid & 15;
  float c[4][4] = {};
  for (int k0 = 0; k0 < DM; k0 += 16) {
#pragma unroll
    for (int p = 0; p < 4; ++p) {
      int e = tid + p * 256;
      int row = e >> 4, kk = e & 15;
      size_t idx = (size_t)(m0 + row) * DM + k0 + kk;
      As[kk][row] = Vp[idx] * gk[b * DM + k0 + kk] + Qs[idx];
    }
#pragma unroll
    for (int p = 0; p < 4; ++p) {
      int e = tid + p * 256;
      int kk = e >> 6, col = e & 63;
      Ws[kk][col] = wo[(size_t)(k0 + kk) * DM + n0 + col];
    }
    __syncthreads();
#pragma unroll
    for (int kk = 0; kk < 16; ++kk) {
      float4 av = *reinterpret_cast<const float4*>(&As[kk][ty * 4]);
      float4 bv = *reinterpret_cast<const float4*>(&Ws[kk][tx * 4]);
      float a[4] = {av.x, av.y, av.z, av.w};
      float bb[4] = {bv.x, bv.y, bv.z, bv.w};
#pragma unroll
      for (int i = 0; i < 4; ++i)
#pragma unroll
        for (int j = 0; j < 4; ++j) c[i][j] += a[i] * bb[j];
    }
    __syncthreads();
  }
#pragma unroll
  for (int i = 0; i < 4; ++i) {
    const int r = m0 + ty * 4 + i;
#pragma unroll
    for (int j = 0; j < 4; ++j) {
      const int n = n0 + tx * 4 + j;
      out[(size_t)r * DM + n] = c[i][j] + bo[n];
    }
  }
}

extern "C" void kernel_launch(void* const* d_in, const int* in_sizes, int n_in,
                              void* d_out, int out_size, void* d_ws, size_t ws_size,
                              hipStream_t stream) {
  // input order: v k q mask wq bq wk bk wv bv gqw gkw wo bo
  const float* v   = (const float*)d_in[0];
  const float* k   = (const float*)d_in[1];
  const float* q   = (const float*)d_in[2];
  const float* wq  = (const float*)d_in[4];
  const float* bq  = (const float*)d_in[5];
  const float* wk  = (const float*)d_in[6];
  const float* bk  = (const float*)d_in[7];
  const float* wv  = (const float*)d_in[8];
  const float* bv  = (const float*)d_in[9];
  const float* gqw = (const float*)d_in[10];
  const float* gkw = (const float*)d_in[11];
  const float* wo  = (const float*)d_in[12];
  const float* bo  = (const float*)d_in[13];
  float* out = (float*)d_out;
  float* ws  = (float*)d_ws;

  float* qr = ws + WS_QR;
  float* kr = ws + WS_KR;
  float* G  = ws + WS_G;
  float* gq = ws + WS_GQ;
  float* gk = ws + WS_GK;
  float* Qs = ws + WS_QS;
  float* Vp = ws + WS_VP;

  // zero the atomic-accumulated regions (qr, kr, G): first 8194 floats
  hipMemsetAsync(d_ws, 0, (8192 + 2) * sizeof(float), stream);

  // K1: weighted seq reductions of raw q, k
  k_reduce<<<dim3(BATCH, DM / 256, 16), 256, 0, stream>>>(q, k, gqw, gkw, qr, kr, G);

  // K2: gq, gk
  k_globalvec<<<dim3(BATCH, DM / 256), 256, 0, stream>>>(wq, bq, wk, bk, qr, kr, G, gq, gk);

  // K3: Qs = (q@wq+bq)*gqw[s] ; Vp = v@wv+bv
  k_proj<true><<<dim3(M_TOT / 64, DM / 64), 256, 0, stream>>>(q, wq, bq, gqw, Qs);
  k_proj<false><<<dim3(M_TOT / 64, DM / 64), 256, 0, stream>>>(v, wv, bv, nullptr, Vp);

  // K4: out = (Vp*gk + Qs) @ wo + bo
  k_out<<<dim3(M_TOT / 64, DM / 64), 256, 0, stream>>>(Vp, Qs, gk, wo, bo, out);
}

// Round 2
// 209.165 us; speedup vs baseline: 3.9565x; 3.9565x over previous
//
#include <hip/hip_runtime.h>

#define DM 1024
#define BATCH 4
#define SEQ 2048
#define M_TOT (BATCH*SEQ)

typedef unsigned short ushort_t;
typedef __bf16 bf16x8 __attribute__((ext_vector_type(8)));
typedef float f32x4 __attribute__((ext_vector_type(4)));
typedef unsigned short u16x8 __attribute__((ext_vector_type(8)));

__device__ __forceinline__ ushort_t f2bf(float f) {
  unsigned u = __builtin_bit_cast(unsigned, f);
  u = (u + 0x7fffu + ((u >> 16) & 1u)) >> 16;
  return (ushort_t)u;
}
__device__ __forceinline__ float bf2f(ushort_t h) {
  unsigned u = ((unsigned)h) << 16;
  return __builtin_bit_cast(float, u);
}

// async global->LDS, 16B per lane, wave-uniform LDS base + lane*16
#define GLL(gp, lp)                                                            \
  __builtin_amdgcn_global_load_lds(                                            \
      (const __attribute__((address_space(1))) unsigned int*)(const void*)(gp),\
      (__attribute__((address_space(3))) unsigned int*)(void*)(lp), 16, 0, 0)

// ---------------------------------------------------------------------------
// K1: qr[b,:] = sum_s gqw[s]*q[b,s,:]; kr likewise; G = [sum gqw, sum gkw]
__global__ void k_reduce(const float* __restrict__ q, const float* __restrict__ k,
                         const float* __restrict__ gqw, const float* __restrict__ gkw,
                         float* __restrict__ qr, float* __restrict__ kr,
                         float* __restrict__ G) {
  const int b = blockIdx.x, dch = blockIdx.y, sch = blockIdx.z;
  const int d = dch * 256 + threadIdx.x;
  const int s0 = sch * (SEQ / 16);
  const float* qp = q + ((size_t)b * SEQ + s0) * DM + d;
  const float* kp = k + ((size_t)b * SEQ + s0) * DM + d;
  float aq = 0.f, ak = 0.f;
  for (int i = 0; i < SEQ / 16; ++i) {
    aq += gqw[s0 + i] * qp[(size_t)i * DM];
    ak += gkw[s0 + i] * kp[(size_t)i * DM];
  }
  atomicAdd(&qr[b * DM + d], aq);
  atomicAdd(&kr[b * DM + d], ak);
  if (b == 0 && dch == 0 && threadIdx.x < SEQ / 16) {
    atomicAdd(&G[0], gqw[s0 + threadIdx.x]);
    atomicAdd(&G[1], gkw[s0 + threadIdx.x]);
  }
}

// K2: gq[b,d] = qr[b,:]@wq[:,d] + bq[d]*G0 ; gk[b,d] = gq * (kr[b,:]@wk[:,d] + bk[d]*G1)
__global__ void k_globalvec(const float* __restrict__ wq, const float* __restrict__ bq,
                            const float* __restrict__ wk, const float* __restrict__ bk,
                            const float* __restrict__ qr, const float* __restrict__ kr,
                            const float* __restrict__ G,
                            float* __restrict__ gq, float* __restrict__ gk) {
  const int b = blockIdx.x;
  const int d = blockIdx.y * 256 + threadIdx.x;
  __shared__ float sqr[DM], skr[DM];
  for (int i = threadIdx.x; i < DM; i += 256) {
    sqr[i] = qr[b * DM + i];
    skr[i] = kr[b * DM + i];
  }
  __syncthreads();
  float accq = 0.f, acck = 0.f;
  for (int kk = 0; kk < DM; ++kk) {
    accq += sqr[kk] * wq[(size_t)kk * DM + d];
    acck += skr[kk] * wk[(size_t)kk * DM + d];
  }
  const float gqv = accq + bq[d] * G[0];
  const float gkr = acck + bk[d] * G[1];
  gq[b * DM + d] = gqv;
  gk[b * DM + d] = gqv * gkr;
}

// K3: fp32 -> bf16 bulk convert, 8 elems/thread
__global__ void k_conv(const float* __restrict__ x, ushort_t* __restrict__ y) {
  size_t i = (size_t)blockIdx.x * 256 + threadIdx.x;
  const float4* p = (const float4*)x + i * 2;
  float4 a = p[0], b = p[1];
  u16x8 o;
  o[0] = f2bf(a.x); o[1] = f2bf(a.y); o[2] = f2bf(a.z); o[3] = f2bf(a.w);
  o[4] = f2bf(b.x); o[5] = f2bf(b.y); o[6] = f2bf(b.z); o[7] = f2bf(b.w);
  *(u16x8*)(y + i * 8) = o;
}

// K4: transpose-convert weight [K][N] fp32 -> [N][K] bf16 (3 weights via blockIdx.z)
__global__ void k_trans(const float* __restrict__ w0, const float* __restrict__ w1,
                        const float* __restrict__ w2,
                        ushort_t* __restrict__ t0, ushort_t* __restrict__ t1,
                        ushort_t* __restrict__ t2) {
  __shared__ float ls[32][33];
  const float* W = blockIdx.z == 0 ? w0 : (blockIdx.z == 1 ? w1 : w2);
  ushort_t* T = blockIdx.z == 0 ? t0 : (blockIdx.z == 1 ? t1 : t2);
  const int bi = blockIdx.x, bj = blockIdx.y;
#pragma unroll
  for (int p = 0; p < 4; ++p) {
    int e = threadIdx.x + p * 256;
    int r = e >> 5, c = e & 31;
    ls[r][c] = W[(size_t)(bi * 32 + r) * DM + bj * 32 + c];
  }
  __syncthreads();
#pragma unroll
  for (int p = 0; p < 4; ++p) {
    int e = threadIdx.x + p * 256;
    int r = e >> 5, c = e & 31;
    T[(size_t)(bj * 32 + r) * DM + bi * 32 + c] = f2bf(ls[c][r]);
  }
}

// ---------------------------------------------------------------------------
// K5: bf16 MFMA GEMM, m97 structure: 128x128 tile, BK=32, 4 waves, 4x4 frags.
// D[m][n] = sum_k A[m][k] * Bt[n][k]  (+ fused epilogue per MODE)
// MODE 0: Out(bf16) = (D + bias[n]) * rs[m & (SEQ-1)]          (Q proj * gqw)
// MODE 1: Out(bf16) = (D + bias[n]) * gk[b][n] + Qs[m][n]      (V proj -> mid)
// MODE 2: Out(f32)  =  D + bias[n]                             (out proj)
template <int MODE>
__global__ void k_gemm(const ushort_t* __restrict__ A, const ushort_t* __restrict__ Bt,
                       const float* __restrict__ bias, const float* __restrict__ rs,
                       const float* __restrict__ gk, const ushort_t* __restrict__ Qs,
                       void* __restrict__ OutV) {
  __shared__ __align__(16) ushort_t lsA[128 * 32];
  __shared__ __align__(16) ushort_t lsB[128 * 32];
  const int tid = threadIdx.x;
  const int w = tid >> 6, lane = tid & 63;
  const int m0 = blockIdx.x * 128, n0 = blockIdx.y * 128;
  const int wr = w >> 1, wc = w & 1;

  // staging: 8KB per tile = 8 chunks of 64 lanes x 16B; wave w stages chunks 2w, 2w+1
  const int c0 = w * 2, c1 = c0 + 1;
  const int e0 = c0 * 64 + lane, e1 = c1 * 64 + lane;
  const ushort_t* gA0 = A + (size_t)(m0 + (e0 >> 2)) * DM + (e0 & 3) * 8;
  const ushort_t* gA1 = A + (size_t)(m0 + (e1 >> 2)) * DM + (e1 & 3) * 8;
  const ushort_t* gB0 = Bt + (size_t)(n0 + (e0 >> 2)) * DM + (e0 & 3) * 8;
  const ushort_t* gB1 = Bt + (size_t)(n0 + (e1 >> 2)) * DM + (e1 & 3) * 8;

  int aoff[4], boff[4];
#pragma unroll
  for (int i = 0; i < 4; ++i) {
    aoff[i] = (wr * 64 + i * 16 + (lane & 15)) * 32 + (lane >> 4) * 8;
    boff[i] = (wc * 64 + i * 16 + (lane & 15)) * 32 + (lane >> 4) * 8;
  }

  f32x4 acc[4][4];
#pragma unroll
  for (int i = 0; i < 4; ++i)
#pragma unroll
    for (int j = 0; j < 4; ++j) acc[i][j] = (f32x4){0.f, 0.f, 0.f, 0.f};

#pragma unroll 1
  for (int k0 = 0; k0 < DM; k0 += 32) {
    GLL(gA0, lsA + c0 * 512);
    GLL(gA1, lsA + c1 * 512);
    GLL(gB0, lsB + c0 * 512);
    GLL(gB1, lsB + c1 * 512);
    gA0 += 32; gA1 += 32; gB0 += 32; gB1 += 32;
    __syncthreads();  // drains vmcnt before barrier (compiler-inserted)
    bf16x8 av[4], bv[4];
#pragma unroll
    for (int i = 0; i < 4; ++i) av[i] = *(const bf16x8*)(lsA + aoff[i]);
#pragma unroll
    for (int j = 0; j < 4; ++j) bv[j] = *(const bf16x8*)(lsB + boff[j]);
#pragma unroll
    for (int i = 0; i < 4; ++i)
#pragma unroll
      for (int j = 0; j < 4; ++j)
        acc[i][j] = __builtin_amdgcn_mfma_f32_16x16x32_bf16(av[i], bv[j], acc[i][j], 0, 0, 0);
    __syncthreads();
  }

  // epilogue: C/D layout col = lane&15, row = (lane>>4)*4 + reg  [m89/m91]
  const int lr = (lane >> 4) * 4, lc = lane & 15;
  const int rbase = m0 + wr * 64, cbase = n0 + wc * 64;
  if constexpr (MODE == 0) {
    ushort_t* Out = (ushort_t*)OutV;
#pragma unroll
    for (int j = 0; j < 4; ++j) {
      const int col = cbase + j * 16 + lc;
      const float bs = bias[col];
#pragma unroll
      for (int i = 0; i < 4; ++i)
#pragma unroll
        for (int t = 0; t < 4; ++t) {
          const int row = rbase + i * 16 + lr + t;
          Out[(size_t)row * DM + col] = f2bf((acc[i][j][t] + bs) * rs[row & (SEQ - 1)]);
        }
    }
  } else if constexpr (MODE == 1) {
    ushort_t* Out = (ushort_t*)OutV;
    const int b = m0 >> 11;  // 2048 % 128 == 0: batch uniform per block
#pragma unroll
    for (int j = 0; j < 4; ++j) {
      const int col = cbase + j * 16 + lc;
      const float bs = bias[col];
      const float gkv = gk[b * DM + col];
#pragma unroll
      for (int i = 0; i < 4; ++i)
#pragma unroll
        for (int t = 0; t < 4; ++t) {
          const int row = rbase + i * 16 + lr + t;
          const size_t idx = (size_t)row * DM + col;
          Out[idx] = f2bf((acc[i][j][t] + bs) * gkv + bf2f(Qs[idx]));
        }
    }
  } else {
    float* Out = (float*)OutV;
#pragma unroll
    for (int j = 0; j < 4; ++j) {
      const int col = cbase + j * 16 + lc;
      const float bs = bias[col];
#pragma unroll
      for (int i = 0; i < 4; ++i)
#pragma unroll
        for (int t = 0; t < 4; ++t) {
          const int row = rbase + i * 16 + lr + t;
          Out[(size_t)row * DM + col] = acc[i][j][t] + bs;
        }
    }
  }
}

// ---------------------------------------------------------------------------
extern "C" void kernel_launch(void* const* d_in, const int* in_sizes, int n_in,
                              void* d_out, int out_size, void* d_ws, size_t ws_size,
                              hipStream_t stream) {
  // input order: v k q mask wq bq wk bk wv bv gqw gkw wo bo
  const float* v   = (const float*)d_in[0];
  const float* k   = (const float*)d_in[1];
  const float* q   = (const float*)d_in[2];
  const float* wq  = (const float*)d_in[4];
  const float* bq  = (const float*)d_in[5];
  const float* wk  = (const float*)d_in[6];
  const float* bk  = (const float*)d_in[7];
  const float* wv  = (const float*)d_in[8];
  const float* bv  = (const float*)d_in[9];
  const float* gqw = (const float*)d_in[10];
  const float* gkw = (const float*)d_in[11];
  const float* wo  = (const float*)d_in[12];
  const float* bo  = (const float*)d_in[13];
  float* out = (float*)d_out;
  float* wsf = (float*)d_ws;

  // fp32 scratch
  float* qr = wsf + 0;
  float* kr = wsf + 4096;
  float* gq = wsf + 8192;
  float* gk = wsf + 12288;
  float* G  = wsf + 16384;  // 2 floats
  // bf16 scratch (byte offset 128 KiB)
  ushort_t* qb  = (ushort_t*)((char*)d_ws + (1 << 17));  // 16MB  (reused as midB)
  ushort_t* vb  = qb + (size_t)M_TOT * DM;               // 16MB
  ushort_t* QsB = vb + (size_t)M_TOT * DM;               // 16MB
  ushort_t* wqT = QsB + (size_t)M_TOT * DM;              // 2MB
  ushort_t* wvT = wqT + (size_t)DM * DM;
  ushort_t* woT = wvT + (size_t)DM * DM;
  ushort_t* midB = qb;  // alias: qb dead after GEMM<0>

  hipMemsetAsync(d_ws, 0, (16384 + 2) * sizeof(float), stream);

  k_reduce<<<dim3(BATCH, DM / 256, 16), 256, 0, stream>>>(q, k, gqw, gkw, qr, kr, G);
  k_globalvec<<<dim3(BATCH, DM / 256), 256, 0, stream>>>(wq, bq, wk, bk, qr, kr, G, gq, gk);

  k_conv<<<(M_TOT * (DM / 8)) / 256, 256, 0, stream>>>(q, qb);
  k_conv<<<(M_TOT * (DM / 8)) / 256, 256, 0, stream>>>(v, vb);
  k_trans<<<dim3(32, 32, 3), 256, 0, stream>>>(wq, wv, wo, wqT, wvT, woT);

  // Qs = (q@wq + bq) * gqw[s]
  k_gemm<0><<<dim3(M_TOT / 128, DM / 128), 256, 0, stream>>>(qb, wqT, bq, gqw, nullptr, nullptr, QsB);
  // mid = (v@wv + bv) * gk + Qs
  k_gemm<1><<<dim3(M_TOT / 128, DM / 128), 256, 0, stream>>>(vb, wvT, bv, nullptr, gk, QsB, midB);
  // out = mid@wo + bo
  k_gemm<2><<<dim3(M_TOT / 128, DM / 128), 256, 0, stream>>>(midB, woT, bo, nullptr, nullptr, nullptr, out);
}

// Round 4
// 155.694 us; speedup vs baseline: 5.3153x; 1.3434x over previous
//
#include <hip/hip_runtime.h>

#define DM 1024
#define BATCH 4
#define SEQ 2048
#define M_TOT (BATCH*SEQ)

typedef unsigned short ushort_t;
typedef __bf16 bf16x8 __attribute__((ext_vector_type(8)));
typedef float f32x4 __attribute__((ext_vector_type(4)));
typedef unsigned short u16x8 __attribute__((ext_vector_type(8)));

__device__ __forceinline__ ushort_t f2bf(float f) {
  unsigned u = __builtin_bit_cast(unsigned, f);
  u = (u + 0x7fffu + ((u >> 16) & 1u)) >> 16;
  return (ushort_t)u;
}
__device__ __forceinline__ float bf2f(ushort_t h) {
  unsigned u = ((unsigned)h) << 16;
  return __builtin_bit_cast(float, u);
}

// async global->LDS, 16B per lane, wave-uniform LDS base + lane*16
#define GLL(gp, lp)                                                            \
  __builtin_amdgcn_global_load_lds(                                            \
      (const __attribute__((address_space(1))) unsigned int*)(const void*)(gp),\
      (__attribute__((address_space(3))) unsigned int*)(void*)(lp), 16, 0, 0)

// ---------------------------------------------------------------------------
// K1: qr[b,:] = sum_s gqw[s]*q[b,s,:]; kr likewise; G = [sum gqw, sum gkw]
//     + fused q -> bf16 conversion (qb)
__global__ void k_reduce(const float* __restrict__ q, const float* __restrict__ k,
                         const float* __restrict__ gqw, const float* __restrict__ gkw,
                         float* __restrict__ qr, float* __restrict__ kr,
                         float* __restrict__ G, ushort_t* __restrict__ qb) {
  const int b = blockIdx.x, dch = blockIdx.y, sch = blockIdx.z;
  const int d = dch * 256 + threadIdx.x;
  const int s0 = sch * (SEQ / 16);
  const size_t base = ((size_t)b * SEQ + s0) * DM + d;
  const float* qp = q + base;
  const float* kp = k + base;
  float aq = 0.f, ak = 0.f;
  for (int i = 0; i < SEQ / 16; ++i) {
    const float qv = qp[(size_t)i * DM];
    aq += gqw[s0 + i] * qv;
    ak += gkw[s0 + i] * kp[(size_t)i * DM];
    qb[base + (size_t)i * DM] = f2bf(qv);
  }
  atomicAdd(&qr[b * DM + d], aq);
  atomicAdd(&kr[b * DM + d], ak);
  if (b == 0 && dch == 0 && threadIdx.x < SEQ / 16) {
    atomicAdd(&G[0], gqw[s0 + threadIdx.x]);
    atomicAdd(&G[1], gkw[s0 + threadIdx.x]);
  }
}

// K2a: partial GEMV over K-chunks: qacc[b,d] += sum_{kk in chunk} qr[b,kk]*wq[kk,d]
// grid (DM/256, DM/32) = (4, 32), block 256. Coalesced weight reads, read-once.
__global__ void k_gpart(const float* __restrict__ wq, const float* __restrict__ wk,
                        const float* __restrict__ qr, const float* __restrict__ kr,
                        float* __restrict__ qacc, float* __restrict__ kacc) {
  const int d = blockIdx.x * 256 + threadIdx.x;
  const int k0 = blockIdx.y * 32;
  __shared__ float sq[4][32], sk[4][32];
  if (threadIdx.x < 128) {
    const int b = threadIdx.x >> 5, kk = threadIdx.x & 31;
    sq[b][kk] = qr[b * DM + k0 + kk];
    sk[b][kk] = kr[b * DM + k0 + kk];
  }
  __syncthreads();
  float aq[4] = {0.f, 0.f, 0.f, 0.f}, ak[4] = {0.f, 0.f, 0.f, 0.f};
#pragma unroll 8
  for (int kk = 0; kk < 32; ++kk) {
    const float wqv = wq[(size_t)(k0 + kk) * DM + d];
    const float wkv = wk[(size_t)(k0 + kk) * DM + d];
#pragma unroll
    for (int b = 0; b < 4; ++b) {
      aq[b] += sq[b][kk] * wqv;
      ak[b] += sk[b][kk] * wkv;
    }
  }
#pragma unroll
  for (int b = 0; b < 4; ++b) {
    atomicAdd(&qacc[b * DM + d], aq[b]);
    atomicAdd(&kacc[b * DM + d], ak[b]);
  }
}

// K2b: gk[b,d] = (qacc + bq[d]*G0) * (kacc + bk[d]*G1)
__global__ void k_gfin(const float* __restrict__ qacc, const float* __restrict__ kacc,
                       const float* __restrict__ bq, const float* __restrict__ bk,
                       const float* __restrict__ G, float* __restrict__ gk) {
  const int i = blockIdx.x * 256 + threadIdx.x;  // 0 .. 4*DM
  const int d = i & (DM - 1);
  const float gqv = qacc[i] + bq[d] * G[0];
  const float gkr = kacc[i] + bk[d] * G[1];
  gk[i] = gqv * gkr;
}

// K3: fp32 -> bf16 bulk convert, 8 elems/thread (v only; q fused into k_reduce)
__global__ void k_conv(const float* __restrict__ x, ushort_t* __restrict__ y) {
  size_t i = (size_t)blockIdx.x * 256 + threadIdx.x;
  const float4* p = (const float4*)x + i * 2;
  float4 a = p[0], b = p[1];
  u16x8 o;
  o[0] = f2bf(a.x); o[1] = f2bf(a.y); o[2] = f2bf(a.z); o[3] = f2bf(a.w);
  o[4] = f2bf(b.x); o[5] = f2bf(b.y); o[6] = f2bf(b.z); o[7] = f2bf(b.w);
  *(u16x8*)(y + i * 8) = o;
}

// K4: transpose-convert weight [K][N] fp32 -> [N][K] bf16 (3 weights via blockIdx.z)
__global__ void k_trans(const float* __restrict__ w0, const float* __restrict__ w1,
                        const float* __restrict__ w2,
                        ushort_t* __restrict__ t0, ushort_t* __restrict__ t1,
                        ushort_t* __restrict__ t2) {
  __shared__ float ls[32][33];
  const float* W = blockIdx.z == 0 ? w0 : (blockIdx.z == 1 ? w1 : w2);
  ushort_t* T = blockIdx.z == 0 ? t0 : (blockIdx.z == 1 ? t1 : t2);
  const int bi = blockIdx.x, bj = blockIdx.y;
#pragma unroll
  for (int p = 0; p < 4; ++p) {
    int e = threadIdx.x + p * 256;
    int r = e >> 5, c = e & 31;
    ls[r][c] = W[(size_t)(bi * 32 + r) * DM + bj * 32 + c];
  }
  __syncthreads();
#pragma unroll
  for (int p = 0; p < 4; ++p) {
    int e = threadIdx.x + p * 256;
    int r = e >> 5, c = e & 31;
    T[(size_t)(bj * 32 + r) * DM + bi * 32 + c] = f2bf(ls[c][r]);
  }
}

// ---------------------------------------------------------------------------
// K5: bf16 MFMA GEMM, m97 structure: 128x128 tile, BK=32, 4 waves, 4x4 frags.
// D[m][n] = sum_k A[m][k] * Bt[n][k]  (+ fused epilogue per MODE)
// MODE 0: Out(bf16) = (D + bias[n]) * rs[m & (SEQ-1)]          (Q proj * gqw)
// MODE 1: Out(bf16) = (D + bias[n]) * gk[b][n] + Qs[m][n]      (V proj -> mid)
// MODE 2: Out(f32)  =  D + bias[n]                             (out proj)
template <int MODE>
__global__ void k_gemm(const ushort_t* __restrict__ A, const ushort_t* __restrict__ Bt,
                       const float* __restrict__ bias, const float* __restrict__ rs,
                       const float* __restrict__ gk, const ushort_t* __restrict__ Qs,
                       void* __restrict__ OutV) {
  __shared__ __align__(16) ushort_t lsA[128 * 32];
  __shared__ __align__(16) ushort_t lsB[128 * 32];
  const int tid = threadIdx.x;
  const int w = tid >> 6, lane = tid & 63;
  const int m0 = blockIdx.x * 128, n0 = blockIdx.y * 128;
  const int wr = w >> 1, wc = w & 1;

  // staging: 8KB per tile = 8 chunks of 64 lanes x 16B; wave w stages chunks 2w, 2w+1
  const int c0 = w * 2, c1 = c0 + 1;
  const int e0 = c0 * 64 + lane, e1 = c1 * 64 + lane;
  const ushort_t* gA0 = A + (size_t)(m0 + (e0 >> 2)) * DM + (e0 & 3) * 8;
  const ushort_t* gA1 = A + (size_t)(m0 + (e1 >> 2)) * DM + (e1 & 3) * 8;
  const ushort_t* gB0 = Bt + (size_t)(n0 + (e0 >> 2)) * DM + (e0 & 3) * 8;
  const ushort_t* gB1 = Bt + (size_t)(n0 + (e1 >> 2)) * DM + (e1 & 3) * 8;

  int aoff[4], boff[4];
#pragma unroll
  for (int i = 0; i < 4; ++i) {
    aoff[i] = (wr * 64 + i * 16 + (lane & 15)) * 32 + (lane >> 4) * 8;
    boff[i] = (wc * 64 + i * 16 + (lane & 15)) * 32 + (lane >> 4) * 8;
  }

  f32x4 acc[4][4];
#pragma unroll
  for (int i = 0; i < 4; ++i)
#pragma unroll
    for (int j = 0; j < 4; ++j) acc[i][j] = (f32x4){0.f, 0.f, 0.f, 0.f};

#pragma unroll 1
  for (int k0 = 0; k0 < DM; k0 += 32) {
    GLL(gA0, lsA + c0 * 512);
    GLL(gA1, lsA + c1 * 512);
    GLL(gB0, lsB + c0 * 512);
    GLL(gB1, lsB + c1 * 512);
    gA0 += 32; gA1 += 32; gB0 += 32; gB1 += 32;
    __syncthreads();
    bf16x8 av[4], bv[4];
#pragma unroll
    for (int i = 0; i < 4; ++i) av[i] = *(const bf16x8*)(lsA + aoff[i]);
#pragma unroll
    for (int j = 0; j < 4; ++j) bv[j] = *(const bf16x8*)(lsB + boff[j]);
#pragma unroll
    for (int i = 0; i < 4; ++i)
#pragma unroll
      for (int j = 0; j < 4; ++j)
        acc[i][j] = __builtin_amdgcn_mfma_f32_16x16x32_bf16(av[i], bv[j], acc[i][j], 0, 0, 0);
    __syncthreads();
  }

  // epilogue: C/D layout col = lane&15, row = (lane>>4)*4 + reg  [m89/m91]
  const int lr = (lane >> 4) * 4, lc = lane & 15;
  const int rbase = m0 + wr * 64, cbase = n0 + wc * 64;
  if constexpr (MODE == 0) {
    ushort_t* Out = (ushort_t*)OutV;
#pragma unroll
    for (int j = 0; j < 4; ++j) {
      const int col = cbase + j * 16 + lc;
      const float bs = bias[col];
#pragma unroll
      for (int i = 0; i < 4; ++i)
#pragma unroll
        for (int t = 0; t < 4; ++t) {
          const int row = rbase + i * 16 + lr + t;
          Out[(size_t)row * DM + col] = f2bf((acc[i][j][t] + bs) * rs[row & (SEQ - 1)]);
        }
    }
  } else if constexpr (MODE == 1) {
    ushort_t* Out = (ushort_t*)OutV;
    const int b = m0 >> 11;  // 2048 % 128 == 0: batch uniform per block
#pragma unroll
    for (int j = 0; j < 4; ++j) {
      const int col = cbase + j * 16 + lc;
      const float bs = bias[col];
      const float gkv = gk[b * DM + col];
#pragma unroll
      for (int i = 0; i < 4; ++i)
#pragma unroll
        for (int t = 0; t < 4; ++t) {
          const int row = rbase + i * 16 + lr + t;
          const size_t idx = (size_t)row * DM + col;
          Out[idx] = f2bf((acc[i][j][t] + bs) * gkv + bf2f(Qs[idx]));
        }
    }
  } else {
    float* Out = (float*)OutV;
#pragma unroll
    for (int j = 0; j < 4; ++j) {
      const int col = cbase + j * 16 + lc;
      const float bs = bias[col];
#pragma unroll
      for (int i = 0; i < 4; ++i)
#pragma unroll
        for (int t = 0; t < 4; ++t) {
          const int row = rbase + i * 16 + lr + t;
          Out[(size_t)row * DM + col] = acc[i][j][t] + bs;
        }
    }
  }
}

// ---------------------------------------------------------------------------
extern "C" void kernel_launch(void* const* d_in, const int* in_sizes, int n_in,
                              void* d_out, int out_size, void* d_ws, size_t ws_size,
                              hipStream_t stream) {
  // input order: v k q mask wq bq wk bk wv bv gqw gkw wo bo
  const float* v   = (const float*)d_in[0];
  const float* k   = (const float*)d_in[1];
  const float* q   = (const float*)d_in[2];
  const float* wq  = (const float*)d_in[4];
  const float* bq  = (const float*)d_in[5];
  const float* wk  = (const float*)d_in[6];
  const float* bk  = (const float*)d_in[7];
  const float* wv  = (const float*)d_in[8];
  const float* bv  = (const float*)d_in[9];
  const float* gqw = (const float*)d_in[10];
  const float* gkw = (const float*)d_in[11];
  const float* wo  = (const float*)d_in[12];
  const float* bo  = (const float*)d_in[13];
  float* out = (float*)d_out;
  float* wsf = (float*)d_ws;

  // fp32 scratch (first 16386 floats zeroed: all atomic accumulators)
  float* qr   = wsf + 0;
  float* kr   = wsf + 4096;
  float* qacc = wsf + 8192;
  float* kacc = wsf + 12288;
  float* G    = wsf + 16384;  // 2 floats
  float* gk   = wsf + 16896;  // 4096 floats, written once by k_gfin
  // bf16 scratch (byte offset 128 KiB)
  ushort_t* qb  = (ushort_t*)((char*)d_ws + (1 << 17));  // 16MB (reused as midB)
  ushort_t* vb  = qb + (size_t)M_TOT * DM;               // 16MB
  ushort_t* QsB = vb + (size_t)M_TOT * DM;               // 16MB
  ushort_t* wqT = QsB + (size_t)M_TOT * DM;              // 2MB
  ushort_t* wvT = wqT + (size_t)DM * DM;
  ushort_t* woT = wvT + (size_t)DM * DM;
  ushort_t* midB = qb;  // alias: qb dead after GEMM<0>

  hipMemsetAsync(d_ws, 0, (16384 + 2) * sizeof(float), stream);

  // K1: weighted seq reductions of raw q, k  (+ q -> bf16 fused)
  k_reduce<<<dim3(BATCH, DM / 256, 16), 256, 0, stream>>>(q, k, gqw, gkw, qr, kr, G, qb);

  // K2: gk via K-parallel GEMV + finalize
  k_gpart<<<dim3(DM / 256, DM / 32), 256, 0, stream>>>(wq, wk, qr, kr, qacc, kacc);
  k_gfin<<<(BATCH * DM) / 256, 256, 0, stream>>>(qacc, kacc, bq, bk, G, gk);

  // conversions (v) + weight transposes
  k_conv<<<(M_TOT * (DM / 8)) / 256, 256, 0, stream>>>(v, vb);
  k_trans<<<dim3(32, 32, 3), 256, 0, stream>>>(wq, wv, wo, wqT, wvT, woT);

  // Qs = (q@wq + bq) * gqw[s]
  k_gemm<0><<<dim3(M_TOT / 128, DM / 128), 256, 0, stream>>>(qb, wqT, bq, gqw, nullptr, nullptr, QsB);
  // mid = (v@wv + bv) * gk + Qs
  k_gemm<1><<<dim3(M_TOT / 128, DM / 128), 256, 0, stream>>>(vb, wvT, bv, nullptr, gk, QsB, midB);
  // out = mid@wo + bo
  k_gemm<2><<<dim3(M_TOT / 128, DM / 128), 256, 0, stream>>>(midB, woT, bo, nullptr, nullptr, nullptr, out);
}

// Round 5
// 143.324 us; speedup vs baseline: 5.7741x; 1.0863x over previous
//
#include <hip/hip_runtime.h>

#define DM 1024
#define BATCH 4
#define SEQ 2048
#define M_TOT (BATCH*SEQ)

typedef unsigned short ushort_t;
typedef __bf16 bf16x8 __attribute__((ext_vector_type(8)));
typedef float f32x4 __attribute__((ext_vector_type(4)));
typedef unsigned short u16x8 __attribute__((ext_vector_type(8)));

__device__ __forceinline__ ushort_t f2bf(float f) {
  unsigned u = __builtin_bit_cast(unsigned, f);
  u = (u + 0x7fffu + ((u >> 16) & 1u)) >> 16;
  return (ushort_t)u;
}
__device__ __forceinline__ float bf2f(ushort_t h) {
  unsigned u = ((unsigned)h) << 16;
  return __builtin_bit_cast(float, u);
}

// async global->LDS, 16B per lane, wave-uniform LDS base + lane*16
#define GLL(gp, lp)                                                            \
  __builtin_amdgcn_global_load_lds(                                            \
      (const __attribute__((address_space(1))) unsigned int*)(const void*)(gp),\
      (__attribute__((address_space(3))) unsigned int*)(void*)(lp), 16, 0, 0)

// ---------------------------------------------------------------------------
// K1: qr[b,:] = sum_s gqw[s]*q[b,s,:]; kr likewise; G = [sum gqw, sum gkw]
//     + fused q,v -> bf16 conversion (qb, vb)
__global__ void k_reduce(const float* __restrict__ q, const float* __restrict__ k,
                         const float* __restrict__ v,
                         const float* __restrict__ gqw, const float* __restrict__ gkw,
                         float* __restrict__ qr, float* __restrict__ kr,
                         float* __restrict__ G,
                         ushort_t* __restrict__ qb, ushort_t* __restrict__ vb) {
  const int b = blockIdx.x, dch = blockIdx.y, sch = blockIdx.z;
  const int d = dch * 256 + threadIdx.x;
  const int s0 = sch * (SEQ / 16);
  const size_t base = ((size_t)b * SEQ + s0) * DM + d;
  const float* qp = q + base;
  const float* kp = k + base;
  const float* vp = v + base;
  float aq = 0.f, ak = 0.f;
  for (int i = 0; i < SEQ / 16; ++i) {
    const float qv = qp[(size_t)i * DM];
    aq += gqw[s0 + i] * qv;
    ak += gkw[s0 + i] * kp[(size_t)i * DM];
    qb[base + (size_t)i * DM] = f2bf(qv);
    vb[base + (size_t)i * DM] = f2bf(vp[(size_t)i * DM]);
  }
  atomicAdd(&qr[b * DM + d], aq);
  atomicAdd(&kr[b * DM + d], ak);
  if (b == 0 && dch == 0 && threadIdx.x < SEQ / 16) {
    atomicAdd(&G[0], gqw[s0 + threadIdx.x]);
    atomicAdd(&G[1], gkw[s0 + threadIdx.x]);
  }
}

// K2a: partial GEMV over K-chunks (coalesced weight reads, read-once)
__global__ void k_gpart(const float* __restrict__ wq, const float* __restrict__ wk,
                        const float* __restrict__ qr, const float* __restrict__ kr,
                        float* __restrict__ qacc, float* __restrict__ kacc) {
  const int d = blockIdx.x * 256 + threadIdx.x;
  const int k0 = blockIdx.y * 32;
  __shared__ float sq[4][32], sk[4][32];
  if (threadIdx.x < 128) {
    const int b = threadIdx.x >> 5, kk = threadIdx.x & 31;
    sq[b][kk] = qr[b * DM + k0 + kk];
    sk[b][kk] = kr[b * DM + k0 + kk];
  }
  __syncthreads();
  float aq[4] = {0.f, 0.f, 0.f, 0.f}, ak[4] = {0.f, 0.f, 0.f, 0.f};
#pragma unroll 8
  for (int kk = 0; kk < 32; ++kk) {
    const float wqv = wq[(size_t)(k0 + kk) * DM + d];
    const float wkv = wk[(size_t)(k0 + kk) * DM + d];
#pragma unroll
    for (int b = 0; b < 4; ++b) {
      aq[b] += sq[b][kk] * wqv;
      ak[b] += sk[b][kk] * wkv;
    }
  }
#pragma unroll
  for (int b = 0; b < 4; ++b) {
    atomicAdd(&qacc[b * DM + d], aq[b]);
    atomicAdd(&kacc[b * DM + d], ak[b]);
  }
}

// K2b: gk[b,d] = (qacc + bq[d]*G0) * (kacc + bk[d]*G1)
__global__ void k_gfin(const float* __restrict__ qacc, const float* __restrict__ kacc,
                       const float* __restrict__ bq, const float* __restrict__ bk,
                       const float* __restrict__ G, float* __restrict__ gk) {
  const int i = blockIdx.x * 256 + threadIdx.x;
  const int d = i & (DM - 1);
  const float gqv = qacc[i] + bq[d] * G[0];
  const float gkr = kacc[i] + bk[d] * G[1];
  gk[i] = gqv * gkr;
}

// K4: transpose-convert weight [K][N] fp32 -> [N][K] bf16 (3 weights via blockIdx.z)
__global__ void k_trans(const float* __restrict__ w0, const float* __restrict__ w1,
                        const float* __restrict__ w2,
                        ushort_t* __restrict__ t0, ushort_t* __restrict__ t1,
                        ushort_t* __restrict__ t2) {
  __shared__ float ls[32][33];
  const float* W = blockIdx.z == 0 ? w0 : (blockIdx.z == 1 ? w1 : w2);
  ushort_t* T = blockIdx.z == 0 ? t0 : (blockIdx.z == 1 ? t1 : t2);
  const int bi = blockIdx.x, bj = blockIdx.y;
#pragma unroll
  for (int p = 0; p < 4; ++p) {
    int e = threadIdx.x + p * 256;
    int r = e >> 5, c = e & 31;
    ls[r][c] = W[(size_t)(bi * 32 + r) * DM + bj * 32 + c];
  }
  __syncthreads();
#pragma unroll
  for (int p = 0; p < 4; ++p) {
    int e = threadIdx.x + p * 256;
    int r = e >> 5, c = e & 31;
    T[(size_t)(bj * 32 + r) * DM + bi * 32 + c] = f2bf(ls[c][r]);
  }
}

// K6: mid = Vp * gk[b][col] + Qs   (bf16 in/out, 8 elems/thread)
__global__ void k_mid(const ushort_t* __restrict__ Vp, const ushort_t* __restrict__ Qs,
                      const float* __restrict__ gk, ushort_t* __restrict__ mid) {
  const size_t i = (size_t)blockIdx.x * 256 + threadIdx.x;  // chunk of 8
  const int col8 = (int)(i & 127) * 8;
  const int b = (int)(i >> 18);
  u16x8 vv = *(const u16x8*)(Vp + i * 8);
  u16x8 qq = *(const u16x8*)(Qs + i * 8);
  const float4 g0 = *(const float4*)(gk + b * DM + col8);
  const float4 g1 = *(const float4*)(gk + b * DM + col8 + 4);
  float g[8] = {g0.x, g0.y, g0.z, g0.w, g1.x, g1.y, g1.z, g1.w};
  u16x8 o;
#pragma unroll
  for (int j = 0; j < 8; ++j) o[j] = f2bf(bf2f(vv[j]) * g[j] + bf2f(qq[j]));
  *(u16x8*)(mid + i * 8) = o;
}

// ---------------------------------------------------------------------------
// K5: bf16 MFMA GEMM, 128x128 tile, BK=32, 4 waves, TRIPLE-buffered LDS with
// 2-deep prefetch and counted vmcnt (T3/T4-lite). Raw s_barrier (no vmcnt(0)
// drain). D[m][n] = sum_k A[m][k] * Bt[n][k].
// MODE 0 (grid.z=2): z=0: Out0(bf16) = (D+bias0[n])*rs[m&2047]   (Q proj)
//                    z=1: Out1(bf16) =  D+bias1[n]               (V proj)
// MODE 1:            Out0(f32)  =  D+bias0[n]                    (out proj)
template <int MODE>
__global__ void k_gemm_db(const ushort_t* __restrict__ A0, const ushort_t* __restrict__ B0,
                          const float* __restrict__ bias0,
                          const ushort_t* __restrict__ A1, const ushort_t* __restrict__ B1,
                          const float* __restrict__ bias1,
                          const float* __restrict__ rs,
                          void* __restrict__ Out0V, void* __restrict__ Out1V) {
  __shared__ __align__(16) ushort_t lsA[3][128 * 32];
  __shared__ __align__(16) ushort_t lsB[3][128 * 32];
  const int z = (MODE == 0) ? blockIdx.z : 0;
  const ushort_t* A  = z ? A1 : A0;
  const ushort_t* Bt = z ? B1 : B0;
  const float* bias  = z ? bias1 : bias0;

  const int tid = threadIdx.x;
  const int w = tid >> 6, lane = tid & 63;
  const int m0 = blockIdx.x * 128, n0 = blockIdx.y * 128;
  const int wr = w >> 1, wc = w & 1;

  // staging: 8KB per matrix per tile = 8 chunks of 64 lanes x 16B; wave w: chunks 2w,2w+1
  const int c0 = w * 2, c1 = c0 + 1;
  const int e0 = c0 * 64 + lane, e1 = c1 * 64 + lane;
  const ushort_t* gA0 = A + (size_t)(m0 + (e0 >> 2)) * DM + (e0 & 3) * 8;
  const ushort_t* gA1 = A + (size_t)(m0 + (e1 >> 2)) * DM + (e1 & 3) * 8;
  const ushort_t* gB0 = Bt + (size_t)(n0 + (e0 >> 2)) * DM + (e0 & 3) * 8;
  const ushort_t* gB1 = Bt + (size_t)(n0 + (e1 >> 2)) * DM + (e1 & 3) * 8;

  int aoff[4], boff[4];
#pragma unroll
  for (int i = 0; i < 4; ++i) {
    aoff[i] = (wr * 64 + i * 16 + (lane & 15)) * 32 + (lane >> 4) * 8;
    boff[i] = (wc * 64 + i * 16 + (lane & 15)) * 32 + (lane >> 4) * 8;
  }

  f32x4 acc[4][4];
#pragma unroll
  for (int i = 0; i < 4; ++i)
#pragma unroll
    for (int j = 0; j < 4; ++j) acc[i][j] = (f32x4){0.f, 0.f, 0.f, 0.f};

  // stage tile t into buffer buf; advances global pointers by BK=32
  auto STAGE = [&](int buf) {
    GLL(gA0, &lsA[buf][c0 * 512]);
    GLL(gA1, &lsA[buf][c1 * 512]);
    GLL(gB0, &lsB[buf][c0 * 512]);
    GLL(gB1, &lsB[buf][c1 * 512]);
    gA0 += 32; gA1 += 32; gB0 += 32; gB1 += 32;
  };

  STAGE(0);
  STAGE(1);
  int cur = 0, nxt = 2;
#pragma unroll 1
  for (int t = 0; t < 32; ++t) {
    // wait for tile t's 4 loads (allow tile t+1's 4 to remain outstanding)
    if (t < 31) { asm volatile("s_waitcnt vmcnt(4)" ::: "memory"); }
    else        { asm volatile("s_waitcnt vmcnt(0)" ::: "memory"); }
    __builtin_amdgcn_s_barrier();   // raw barrier: no vmcnt(0) drain
    if (t + 2 < 32) {
      STAGE(nxt);
      nxt = (nxt == 2) ? 0 : nxt + 1;
    }
    bf16x8 av[4], bv[4];
#pragma unroll
    for (int i = 0; i < 4; ++i) av[i] = *(const bf16x8*)(&lsA[cur][aoff[i]]);
#pragma unroll
    for (int j = 0; j < 4; ++j) bv[j] = *(const bf16x8*)(&lsB[cur][boff[j]]);
#pragma unroll
    for (int i = 0; i < 4; ++i)
#pragma unroll
      for (int j = 0; j < 4; ++j)
        acc[i][j] = __builtin_amdgcn_mfma_f32_16x16x32_bf16(av[i], bv[j], acc[i][j], 0, 0, 0);
    cur = (cur == 2) ? 0 : cur + 1;
  }

  // epilogue: C/D layout col = lane&15, row = (lane>>4)*4 + reg  [m89/m91]
  const int lr = (lane >> 4) * 4, lc = lane & 15;
  const int rbase = m0 + wr * 64, cbase = n0 + wc * 64;
  if constexpr (MODE == 0) {
    if (z == 0) {
      ushort_t* Out = (ushort_t*)Out0V;
#pragma unroll
      for (int j = 0; j < 4; ++j) {
        const int col = cbase + j * 16 + lc;
        const float bs = bias[col];
#pragma unroll
        for (int i = 0; i < 4; ++i)
#pragma unroll
          for (int t = 0; t < 4; ++t) {
            const int row = rbase + i * 16 + lr + t;
            Out[(size_t)row * DM + col] = f2bf((acc[i][j][t] + bs) * rs[row & (SEQ - 1)]);
          }
      }
    } else {
      ushort_t* Out = (ushort_t*)Out1V;
#pragma unroll
      for (int j = 0; j < 4; ++j) {
        const int col = cbase + j * 16 + lc;
        const float bs = bias[col];
#pragma unroll
        for (int i = 0; i < 4; ++i)
#pragma unroll
          for (int t = 0; t < 4; ++t) {
            const int row = rbase + i * 16 + lr + t;
            Out[(size_t)row * DM + col] = f2bf(acc[i][j][t] + bs);
          }
      }
    }
  } else {
    float* Out = (float*)Out0V;
#pragma unroll
    for (int j = 0; j < 4; ++j) {
      const int col = cbase + j * 16 + lc;
      const float bs = bias[col];
#pragma unroll
      for (int i = 0; i < 4; ++i)
#pragma unroll
        for (int t = 0; t < 4; ++t) {
          const int row = rbase + i * 16 + lr + t;
          Out[(size_t)row * DM + col] = acc[i][j][t] + bs;
        }
    }
  }
}

// ---------------------------------------------------------------------------
extern "C" void kernel_launch(void* const* d_in, const int* in_sizes, int n_in,
                              void* d_out, int out_size, void* d_ws, size_t ws_size,
                              hipStream_t stream) {
  // input order: v k q mask wq bq wk bk wv bv gqw gkw wo bo
  const float* v   = (const float*)d_in[0];
  const float* k   = (const float*)d_in[1];
  const float* q   = (const float*)d_in[2];
  const float* wq  = (const float*)d_in[4];
  const float* bq  = (const float*)d_in[5];
  const float* wk  = (const float*)d_in[6];
  const float* bk  = (const float*)d_in[7];
  const float* wv  = (const float*)d_in[8];
  const float* bv  = (const float*)d_in[9];
  const float* gqw = (const float*)d_in[10];
  const float* gkw = (const float*)d_in[11];
  const float* wo  = (const float*)d_in[12];
  const float* bo  = (const float*)d_in[13];
  float* out = (float*)d_out;
  float* wsf = (float*)d_ws;

  // fp32 scratch (first 16386 floats zeroed: all atomic accumulators)
  float* qr   = wsf + 0;
  float* kr   = wsf + 4096;
  float* qacc = wsf + 8192;
  float* kacc = wsf + 12288;
  float* G    = wsf + 16384;  // 2 floats
  float* gk   = wsf + 16896;  // 4096 floats, written once by k_gfin
  // bf16 scratch (byte offset 128 KiB)
  ushort_t* qb  = (ushort_t*)((char*)d_ws + (1 << 17));  // 16MB (reused as midB)
  ushort_t* vb  = qb + (size_t)M_TOT * DM;               // 16MB
  ushort_t* QsB = vb + (size_t)M_TOT * DM;               // 16MB
  ushort_t* wqT = QsB + (size_t)M_TOT * DM;              // 2MB
  ushort_t* wvT = wqT + (size_t)DM * DM;
  ushort_t* woT = wvT + (size_t)DM * DM;
  ushort_t* midB = qb;              // alias: qb dead after GEMM01
  ushort_t* VpB  = (ushort_t*)out;  // alias: d_out(32MB f32) holds Vp(16MB bf16)
                                    // until GEMM2 overwrites it with the result

  hipMemsetAsync(d_ws, 0, (16384 + 2) * sizeof(float), stream);

  // K1: weighted seq reductions of raw q,k + q,v -> bf16
  k_reduce<<<dim3(BATCH, DM / 256, 16), 256, 0, stream>>>(q, k, v, gqw, gkw, qr, kr, G, qb, vb);

  // K2: gk via K-parallel GEMV + finalize
  k_gpart<<<dim3(DM / 256, DM / 32), 256, 0, stream>>>(wq, wk, qr, kr, qacc, kacc);
  k_gfin<<<(BATCH * DM) / 256, 256, 0, stream>>>(qacc, kacc, bq, bk, G, gk);

  // weight transposes
  k_trans<<<dim3(32, 32, 3), 256, 0, stream>>>(wq, wv, wo, wqT, wvT, woT);

  // GEMM01 (z-batched): z=0 Qs = (q@wq+bq)*gqw[s]; z=1 Vp = v@wv+bv
  k_gemm_db<0><<<dim3(M_TOT / 128, DM / 128, 2), 256, 0, stream>>>(
      qb, wqT, bq, vb, wvT, bv, gqw, QsB, VpB);

  // mid = Vp*gk + Qs
  k_mid<<<(M_TOT * (DM / 8)) / 256, 256, 0, stream>>>(VpB, QsB, gk, midB);

  // out = mid@wo + bo
  k_gemm_db<1><<<dim3(M_TOT / 128, DM / 128), 256, 0, stream>>>(
      midB, woT, bo, nullptr, nullptr, nullptr, nullptr, out, nullptr);
}

// Round 6
// 143.302 us; speedup vs baseline: 5.7749x; 1.0002x over previous
//
#include <hip/hip_runtime.h>

#define DM 1024
#define BATCH 4
#define SEQ 2048
#define M_TOT (BATCH*SEQ)

typedef unsigned short ushort_t;
typedef __bf16 bf16x8 __attribute__((ext_vector_type(8)));
typedef float f32x4 __attribute__((ext_vector_type(4)));
typedef unsigned short u16x8 __attribute__((ext_vector_type(8)));

__device__ __forceinline__ ushort_t f2bf(float f) {
  unsigned u = __builtin_bit_cast(unsigned, f);
  u = (u + 0x7fffu + ((u >> 16) & 1u)) >> 16;
  return (ushort_t)u;
}
__device__ __forceinline__ float bf2f(ushort_t h) {
  unsigned u = ((unsigned)h) << 16;
  return __builtin_bit_cast(float, u);
}

// async global->LDS, 16B per lane, wave-uniform LDS base + lane*16
#define GLL(gp, lp)                                                            \
  __builtin_amdgcn_global_load_lds(                                            \
      (const __attribute__((address_space(1))) unsigned int*)(const void*)(gp),\
      (__attribute__((address_space(3))) unsigned int*)(void*)(lp), 16, 0, 0)

// ---------------------------------------------------------------------------
// K1: qr[b,:] = sum_s gqw[s]*q[b,s,:]; kr likewise; G = [sum gqw, sum gkw]
//     qb = bf16(gqw[s] * q)   (row-scale folded into A!),  vb = bf16(v)
__global__ void k_reduce(const float* __restrict__ q, const float* __restrict__ k,
                         const float* __restrict__ v,
                         const float* __restrict__ gqw, const float* __restrict__ gkw,
                         float* __restrict__ qr, float* __restrict__ kr,
                         float* __restrict__ G,
                         ushort_t* __restrict__ qb, ushort_t* __restrict__ vb) {
  const int b = blockIdx.x, dch = blockIdx.y, sch = blockIdx.z;
  const int d = dch * 256 + threadIdx.x;
  const int s0 = sch * (SEQ / 16);
  const size_t base = ((size_t)b * SEQ + s0) * DM + d;
  const float* qp = q + base;
  const float* kp = k + base;
  const float* vp = v + base;
  float aq = 0.f, ak = 0.f;
  for (int i = 0; i < SEQ / 16; ++i) {
    const float w = gqw[s0 + i];
    const float qv = qp[(size_t)i * DM];
    aq += w * qv;
    ak += gkw[s0 + i] * kp[(size_t)i * DM];
    qb[base + (size_t)i * DM] = f2bf(w * qv);
    vb[base + (size_t)i * DM] = f2bf(vp[(size_t)i * DM]);
  }
  atomicAdd(&qr[b * DM + d], aq);
  atomicAdd(&kr[b * DM + d], ak);
  if (b == 0 && dch == 0 && threadIdx.x < SEQ / 16) {
    atomicAdd(&G[0], gqw[s0 + threadIdx.x]);
    atomicAdd(&G[1], gkw[s0 + threadIdx.x]);
  }
}

// K2a: partial GEMV over K-chunks (coalesced weight reads, read-once)
__global__ void k_gpart(const float* __restrict__ wq, const float* __restrict__ wk,
                        const float* __restrict__ qr, const float* __restrict__ kr,
                        float* __restrict__ qacc, float* __restrict__ kacc) {
  const int d = blockIdx.x * 256 + threadIdx.x;
  const int k0 = blockIdx.y * 32;
  __shared__ float sq[4][32], sk[4][32];
  if (threadIdx.x < 128) {
    const int b = threadIdx.x >> 5, kk = threadIdx.x & 31;
    sq[b][kk] = qr[b * DM + k0 + kk];
    sk[b][kk] = kr[b * DM + k0 + kk];
  }
  __syncthreads();
  float aq[4] = {0.f, 0.f, 0.f, 0.f}, ak[4] = {0.f, 0.f, 0.f, 0.f};
#pragma unroll 8
  for (int kk = 0; kk < 32; ++kk) {
    const float wqv = wq[(size_t)(k0 + kk) * DM + d];
    const float wkv = wk[(size_t)(k0 + kk) * DM + d];
#pragma unroll
    for (int b = 0; b < 4; ++b) {
      aq[b] += sq[b][kk] * wqv;
      ak[b] += sk[b][kk] * wkv;
    }
  }
#pragma unroll
  for (int b = 0; b < 4; ++b) {
    atomicAdd(&qacc[b * DM + d], aq[b]);
    atomicAdd(&kacc[b * DM + d], ak[b]);
  }
}

// K2b: gk[b,d] = (qacc + bq[d]*G0) * (kacc + bk[d]*G1)
__global__ void k_gfin(const float* __restrict__ qacc, const float* __restrict__ kacc,
                       const float* __restrict__ bq, const float* __restrict__ bk,
                       const float* __restrict__ G, float* __restrict__ gk) {
  const int i = blockIdx.x * 256 + threadIdx.x;
  const int d = i & (DM - 1);
  const float gqv = qacc[i] + bq[d] * G[0];
  const float gkr = kacc[i] + bk[d] * G[1];
  gk[i] = gqv * gkr;
}

// K3: fp32 -> bf16 row-major convert, 8 elems/thread
__global__ void k_conv(const float* __restrict__ x, ushort_t* __restrict__ y) {
  size_t i = (size_t)blockIdx.x * 256 + threadIdx.x;
  const float4* p = (const float4*)x + i * 2;
  float4 a = p[0], b = p[1];
  u16x8 o;
  o[0] = f2bf(a.x); o[1] = f2bf(a.y); o[2] = f2bf(a.z); o[3] = f2bf(a.w);
  o[4] = f2bf(b.x); o[5] = f2bf(b.y); o[6] = f2bf(b.z); o[7] = f2bf(b.w);
  *(u16x8*)(y + i * 8) = o;
}

// K4: transpose-convert wo [K][N] fp32 -> woT [N][K] bf16
__global__ void k_trans(const float* __restrict__ W, ushort_t* __restrict__ T) {
  __shared__ float ls[32][33];
  const int bi = blockIdx.x, bj = blockIdx.y;
#pragma unroll
  for (int p = 0; p < 4; ++p) {
    int e = threadIdx.x + p * 256;
    int r = e >> 5, c = e & 31;
    ls[r][c] = W[(size_t)(bi * 32 + r) * DM + bj * 32 + c];
  }
  __syncthreads();
#pragma unroll
  for (int p = 0; p < 4; ++p) {
    int e = threadIdx.x + p * 256;
    int r = e >> 5, c = e & 31;
    T[(size_t)(bj * 32 + r) * DM + bi * 32 + c] = f2bf(ls[c][r]);
  }
}

// K5: wogT[b][n][j] = woT[n][j] * gk[b][j]   (bf16 out, 8/thread)
__global__ void k_wog(const ushort_t* __restrict__ woT, const float* __restrict__ gk,
                      ushort_t* __restrict__ wogT) {
  const size_t i = (size_t)blockIdx.x * 256 + threadIdx.x;  // chunk of 8
  const size_t c = i * 8;
  const int j0 = (int)(c & (DM - 1));
  const int b = (int)(c >> 20);
  u16x8 wv = *(const u16x8*)(woT + (c & ((1u << 20) - 1)));
  const float4 g0 = *(const float4*)(gk + b * DM + j0);
  const float4 g1 = *(const float4*)(gk + b * DM + j0 + 4);
  float g[8] = {g0.x, g0.y, g0.z, g0.w, g1.x, g1.y, g1.z, g1.w};
  u16x8 o;
#pragma unroll
  for (int j = 0; j < 8; ++j) o[j] = f2bf(bf2f(wv[j]) * g[j]);
  *(u16x8*)(wogT + i * 8) = o;
}

// K6: qbias[n] = sum_j bq[j]*wo[j,n];  vbias[b][n] = sum_j bv[j]*gk[b][j]*wo[j,n]
__global__ void k_bias(const float* __restrict__ wo, const float* __restrict__ bq,
                       const float* __restrict__ bv, const float* __restrict__ gk,
                       float* __restrict__ qbias, float* __restrict__ vbias) {
  const int n = blockIdx.x * 256 + threadIdx.x;
  const int k0 = blockIdx.y * 32;
  float aq = 0.f, av[4] = {0.f, 0.f, 0.f, 0.f};
  for (int kk = 0; kk < 32; ++kk) {
    const float w = wo[(size_t)(k0 + kk) * DM + n];
    aq += bq[k0 + kk] * w;
    const float bw = bv[k0 + kk] * w;
#pragma unroll
    for (int b = 0; b < 4; ++b) av[b] += bw * gk[b * DM + k0 + kk];
  }
  atomicAdd(&qbias[n], aq);
#pragma unroll
  for (int b = 0; b < 4; ++b) atomicAdd(&vbias[b * DM + n], av[b]);
}

// ---------------------------------------------------------------------------
// K7: small weight GEMMs, 128x128 tile, BK=32, triple-buffer 2-deep prefetch.
// z=0: WqoT[n,k] = sum_j woT[n,j]*wq[k,j]
// z>0: WvbT[b][n,k] = sum_j wogT[b][n,j]*wv[k,j]
__global__ void k_small(const ushort_t* __restrict__ woT, const ushort_t* __restrict__ wogT,
                        const ushort_t* __restrict__ wqB, const ushort_t* __restrict__ wvB,
                        ushort_t* __restrict__ WqoT, ushort_t* __restrict__ WvbT) {
  __shared__ __align__(16) ushort_t lsA[3][128 * 32];
  __shared__ __align__(16) ushort_t lsB[3][128 * 32];
  const int z = blockIdx.z;
  const ushort_t* A  = z == 0 ? woT : wogT + (size_t)(z - 1) * (DM * DM);
  const ushort_t* Bt = z == 0 ? wqB : wvB;
  ushort_t* Out      = z == 0 ? WqoT : WvbT + (size_t)(z - 1) * (DM * DM);

  const int tid = threadIdx.x;
  const int w = tid >> 6, lane = tid & 63;
  const int m0 = blockIdx.x * 128, n0 = blockIdx.y * 128;
  const int wr = w >> 1, wc = w & 1;
  const int c0 = w * 2, c1 = c0 + 1;
  const int e0 = c0 * 64 + lane, e1 = c1 * 64 + lane;
  const ushort_t* gA0 = A + (size_t)(m0 + (e0 >> 2)) * DM + (e0 & 3) * 8;
  const ushort_t* gA1 = A + (size_t)(m0 + (e1 >> 2)) * DM + (e1 & 3) * 8;
  const ushort_t* gB0 = Bt + (size_t)(n0 + (e0 >> 2)) * DM + (e0 & 3) * 8;
  const ushort_t* gB1 = Bt + (size_t)(n0 + (e1 >> 2)) * DM + (e1 & 3) * 8;

  int aoff[4], boff[4];
#pragma unroll
  for (int i = 0; i < 4; ++i) {
    aoff[i] = (wr * 64 + i * 16 + (lane & 15)) * 32 + (lane >> 4) * 8;
    boff[i] = (wc * 64 + i * 16 + (lane & 15)) * 32 + (lane >> 4) * 8;
  }

  f32x4 acc[4][4];
#pragma unroll
  for (int i = 0; i < 4; ++i)
#pragma unroll
    for (int j = 0; j < 4; ++j) acc[i][j] = (f32x4){0.f, 0.f, 0.f, 0.f};

  auto STAGE = [&](int tt, int buf) {
    const int o = tt * 32;
    GLL(gA0 + o, &lsA[buf][c0 * 512]);
    GLL(gA1 + o, &lsA[buf][c1 * 512]);
    GLL(gB0 + o, &lsB[buf][c0 * 512]);
    GLL(gB1 + o, &lsB[buf][c1 * 512]);
  };

  STAGE(0, 0);
  STAGE(1, 1);
  int cur = 0, nxt = 2;
#pragma unroll 1
  for (int t = 0; t < 32; ++t) {
    if (t < 31) { asm volatile("s_waitcnt vmcnt(4)" ::: "memory"); }
    else        { asm volatile("s_waitcnt vmcnt(0)" ::: "memory"); }
    __builtin_amdgcn_s_barrier();
    if (t + 2 < 32) {
      STAGE(t + 2, nxt);
      nxt = (nxt == 2) ? 0 : nxt + 1;
    }
    bf16x8 av[4], bv[4];
#pragma unroll
    for (int i = 0; i < 4; ++i) av[i] = *(const bf16x8*)(&lsA[cur][aoff[i]]);
#pragma unroll
    for (int j = 0; j < 4; ++j) bv[j] = *(const bf16x8*)(&lsB[cur][boff[j]]);
#pragma unroll
    for (int i = 0; i < 4; ++i)
#pragma unroll
      for (int j = 0; j < 4; ++j)
        acc[i][j] = __builtin_amdgcn_mfma_f32_16x16x32_bf16(av[i], bv[j], acc[i][j], 0, 0, 0);
    cur = (cur == 2) ? 0 : cur + 1;
  }

  const int lr = (lane >> 4) * 4, lc = lane & 15;
  const int rbase = m0 + wr * 64, cbase = n0 + wc * 64;
#pragma unroll
  for (int j = 0; j < 4; ++j) {
    const int col = cbase + j * 16 + lc;
#pragma unroll
    for (int i = 0; i < 4; ++i)
#pragma unroll
      for (int t = 0; t < 4; ++t) {
        const int row = rbase + i * 16 + lr + t;
        Out[(size_t)row * DM + col] = f2bf(acc[i][j][t]);
      }
  }
}

// ---------------------------------------------------------------------------
// K8: the one big GEMM, K_eff = 2048 (q-side tiles 0..31, v-side 32..63).
// out[m,n] = sum_k qb[m,k]*WqoT[n,k] + sum_k vb[m,k]*WvbT[b][n,k]
//          + gqw[m%SEQ]*qbias[n] + vbias[b][n] + bo[n]
__global__ void k_big(const ushort_t* __restrict__ qb, const ushort_t* __restrict__ vb,
                      const ushort_t* __restrict__ WqoT, const ushort_t* __restrict__ WvbT,
                      const float* __restrict__ gqw, const float* __restrict__ qbias,
                      const float* __restrict__ vbias, const float* __restrict__ bo,
                      float* __restrict__ Out) {
  __shared__ __align__(16) ushort_t lsA[3][128 * 32];
  __shared__ __align__(16) ushort_t lsB[3][128 * 32];
  const int tid = threadIdx.x;
  const int w = tid >> 6, lane = tid & 63;
  const int m0 = blockIdx.x * 128, n0 = blockIdx.y * 128;
  const int b = m0 >> 11;
  const int wr = w >> 1, wc = w & 1;
  const int c0 = w * 2, c1 = c0 + 1;
  const int e0 = c0 * 64 + lane, e1 = c1 * 64 + lane;
  const size_t offA0 = (size_t)(m0 + (e0 >> 2)) * DM + (e0 & 3) * 8;
  const size_t offA1 = (size_t)(m0 + (e1 >> 2)) * DM + (e1 & 3) * 8;
  const size_t offB0 = (size_t)(n0 + (e0 >> 2)) * DM + (e0 & 3) * 8;
  const size_t offB1 = (size_t)(n0 + (e1 >> 2)) * DM + (e1 & 3) * 8;
  const ushort_t* gAq0 = qb + offA0;
  const ushort_t* gAq1 = qb + offA1;
  const ushort_t* gAv0 = vb + offA0;
  const ushort_t* gAv1 = vb + offA1;
  const ushort_t* gBq0 = WqoT + offB0;
  const ushort_t* gBq1 = WqoT + offB1;
  const ushort_t* gBv0 = WvbT + (size_t)b * (DM * DM) + offB0;
  const ushort_t* gBv1 = WvbT + (size_t)b * (DM * DM) + offB1;

  int aoff[4], boff[4];
#pragma unroll
  for (int i = 0; i < 4; ++i) {
    aoff[i] = (wr * 64 + i * 16 + (lane & 15)) * 32 + (lane >> 4) * 8;
    boff[i] = (wc * 64 + i * 16 + (lane & 15)) * 32 + (lane >> 4) * 8;
  }

  f32x4 acc[4][4];
#pragma unroll
  for (int i = 0; i < 4; ++i)
#pragma unroll
    for (int j = 0; j < 4; ++j) acc[i][j] = (f32x4){0.f, 0.f, 0.f, 0.f};

  auto STAGE = [&](int tt, int buf) {
    const ushort_t *a0, *a1, *b0, *b1;
    if (tt < 32) {
      const int o = tt * 32;
      a0 = gAq0 + o; a1 = gAq1 + o; b0 = gBq0 + o; b1 = gBq1 + o;
    } else {
      const int o = (tt - 32) * 32;
      a0 = gAv0 + o; a1 = gAv1 + o; b0 = gBv0 + o; b1 = gBv1 + o;
    }
    GLL(a0, &lsA[buf][c0 * 512]);
    GLL(a1, &lsA[buf][c1 * 512]);
    GLL(b0, &lsB[buf][c0 * 512]);
    GLL(b1, &lsB[buf][c1 * 512]);
  };

  STAGE(0, 0);
  STAGE(1, 1);
  int cur = 0, nxt = 2;
#pragma unroll 1
  for (int t = 0; t < 64; ++t) {
    if (t < 63) { asm volatile("s_waitcnt vmcnt(4)" ::: "memory"); }
    else        { asm volatile("s_waitcnt vmcnt(0)" ::: "memory"); }
    __builtin_amdgcn_s_barrier();
    if (t + 2 < 64) {
      STAGE(t + 2, nxt);
      nxt = (nxt == 2) ? 0 : nxt + 1;
    }
    bf16x8 av[4], bv[4];
#pragma unroll
    for (int i = 0; i < 4; ++i) av[i] = *(const bf16x8*)(&lsA[cur][aoff[i]]);
#pragma unroll
    for (int j = 0; j < 4; ++j) bv[j] = *(const bf16x8*)(&lsB[cur][boff[j]]);
#pragma unroll
    for (int i = 0; i < 4; ++i)
#pragma unroll
      for (int j = 0; j < 4; ++j)
        acc[i][j] = __builtin_amdgcn_mfma_f32_16x16x32_bf16(av[i], bv[j], acc[i][j], 0, 0, 0);
    cur = (cur == 2) ? 0 : cur + 1;
  }

  const int lr = (lane >> 4) * 4, lc = lane & 15;
  const int rbase = m0 + wr * 64, cbase = n0 + wc * 64;
#pragma unroll
  for (int j = 0; j < 4; ++j) {
    const int col = cbase + j * 16 + lc;
    const float qbn = qbias[col];
    const float cb = vbias[b * DM + col] + bo[col];
#pragma unroll
    for (int i = 0; i < 4; ++i)
#pragma unroll
      for (int t = 0; t < 4; ++t) {
        const int row = rbase + i * 16 + lr + t;
        Out[(size_t)row * DM + col] = acc[i][j][t] + gqw[row & (SEQ - 1)] * qbn + cb;
      }
  }
}

// ---------------------------------------------------------------------------
extern "C" void kernel_launch(void* const* d_in, const int* in_sizes, int n_in,
                              void* d_out, int out_size, void* d_ws, size_t ws_size,
                              hipStream_t stream) {
  // input order: v k q mask wq bq wk bk wv bv gqw gkw wo bo
  const float* v   = (const float*)d_in[0];
  const float* k   = (const float*)d_in[1];
  const float* q   = (const float*)d_in[2];
  const float* wq  = (const float*)d_in[4];
  const float* bq  = (const float*)d_in[5];
  const float* wk  = (const float*)d_in[6];
  const float* bk  = (const float*)d_in[7];
  const float* wv  = (const float*)d_in[8];
  const float* bv  = (const float*)d_in[9];
  const float* gqw = (const float*)d_in[10];
  const float* gkw = (const float*)d_in[11];
  const float* wo  = (const float*)d_in[12];
  const float* bo  = (const float*)d_in[13];
  float* out = (float*)d_out;
  float* wsf = (float*)d_ws;

  // fp32 scratch: [qr kr qacc kacc | G | qbias | vbias | gk]
  float* qr    = wsf + 0;
  float* kr    = wsf + 4096;
  float* qacc  = wsf + 8192;
  float* kacc  = wsf + 12288;
  float* G     = wsf + 16384;   // 2 floats
  float* qbias = wsf + 16640;   // 1024
  float* vbias = wsf + 17664;   // 4096
  float* gk    = wsf + 21760;   // 4096 (fully written by k_gfin, no zeroing)
  // bf16 scratch at byte offset 128 KiB (total 48 MB)
  ushort_t* b16  = (ushort_t*)((char*)d_ws + (1 << 17));
  ushort_t* qb   = b16;                                 // 16MB [M][DM] gqw-scaled
  ushort_t* vb   = qb + (size_t)M_TOT * DM;             // 16MB
  ushort_t* wqB  = vb + (size_t)M_TOT * DM;             // 2MB row-major bf16
  ushort_t* wvB  = wqB + (size_t)DM * DM;               // 2MB
  ushort_t* woT  = wvB + (size_t)DM * DM;               // 2MB [N][K]
  ushort_t* WqoT = woT + (size_t)DM * DM;               // 2MB
  ushort_t* WvbT = WqoT + (size_t)DM * DM;              // 8MB [4][N][K]
  ushort_t* wogT = (ushort_t*)out;  // 8MB alias in d_out; dead before k_big writes out

  // zero atomic accumulators: qr..kacc + G + qbias + vbias = 21760 floats
  hipMemsetAsync(d_ws, 0, 21760 * sizeof(float), stream);

  // weight preps (independent of data path)
  k_conv<<<(DM * DM / 8) / 256, 256, 0, stream>>>(wq, wqB);
  k_conv<<<(DM * DM / 8) / 256, 256, 0, stream>>>(wv, wvB);
  k_trans<<<dim3(32, 32), 256, 0, stream>>>(wo, woT);

  // data reductions + bf16 conversions
  k_reduce<<<dim3(BATCH, DM / 256, 16), 256, 0, stream>>>(q, k, v, gqw, gkw, qr, kr, G, qb, vb);

  // gk
  k_gpart<<<dim3(DM / 256, DM / 32), 256, 0, stream>>>(wq, wk, qr, kr, qacc, kacc);
  k_gfin<<<(BATCH * DM) / 256, 256, 0, stream>>>(qacc, kacc, bq, bk, G, gk);

  // composed-weight preps
  k_wog<<<(BATCH * DM * DM / 8) / 256, 256, 0, stream>>>(woT, gk, wogT);
  k_bias<<<dim3(DM / 256, DM / 32), 256, 0, stream>>>(wo, bq, bv, gk, qbias, vbias);

  // small GEMMs: WqoT, WvbT[0..3]
  k_small<<<dim3(8, 8, 5), 256, 0, stream>>>(woT, wogT, wqB, wvB, WqoT, WvbT);

  // the one big GEMM -> out
  k_big<<<dim3(M_TOT / 128, DM / 128), 256, 0, stream>>>(
      qb, vb, WqoT, WvbT, gqw, qbias, vbias, bo, out);
}

// Round 7
// 136.198 us; speedup vs baseline: 6.0761x; 1.0522x over previous
//
#include <hip/hip_runtime.h>

#define DM 1024
#define BATCH 4
#define SEQ 2048
#define M_TOT (BATCH*SEQ)

typedef unsigned short ushort_t;
typedef __bf16 bf16x8 __attribute__((ext_vector_type(8)));
typedef float f32x4 __attribute__((ext_vector_type(4)));
typedef unsigned short u16x8 __attribute__((ext_vector_type(8)));

__device__ __forceinline__ ushort_t f2bf(float f) {
  unsigned u = __builtin_bit_cast(unsigned, f);
  u = (u + 0x7fffu + ((u >> 16) & 1u)) >> 16;
  return (ushort_t)u;
}
__device__ __forceinline__ float bf2f(ushort_t h) {
  unsigned u = ((unsigned)h) << 16;
  return __builtin_bit_cast(float, u);
}

// async global->LDS, 16B per lane, wave-uniform LDS base + lane*16
#define GLL(gp, lp)                                                            \
  __builtin_amdgcn_global_load_lds(                                            \
      (const __attribute__((address_space(1))) unsigned int*)(const void*)(gp),\
      (__attribute__((address_space(3))) unsigned int*)(void*)(lp), 16, 0, 0)

// slot-XOR swizzle: element e (of a 64B-row tile, 4 slots of 8 bf16) sources
// global slot (e&3)^((e>>3)&3); ds_read applies the same XOR -> involution.
__device__ __forceinline__ size_t src_off(int row0, int e) {
  return (size_t)(row0 + (e >> 2)) * DM + (((e & 3) ^ ((e >> 3) & 3)) * 8);
}

// ---------------------------------------------------------------------------
// K1: qr[b,:] = sum_s gqw[s]*q[b,s,:]; kr likewise; G = [sum gqw, sum gkw]
//     qb = bf16(gqw[s] * q)   (row-scale folded into A),  vb = bf16(v)
__global__ void k_reduce(const float* __restrict__ q, const float* __restrict__ k,
                         const float* __restrict__ v,
                         const float* __restrict__ gqw, const float* __restrict__ gkw,
                         float* __restrict__ qr, float* __restrict__ kr,
                         float* __restrict__ G,
                         ushort_t* __restrict__ qb, ushort_t* __restrict__ vb) {
  const int b = blockIdx.x, dch = blockIdx.y, sch = blockIdx.z;
  const int d = dch * 256 + threadIdx.x;
  const int s0 = sch * (SEQ / 16);
  const size_t base = ((size_t)b * SEQ + s0) * DM + d;
  const float* qp = q + base;
  const float* kp = k + base;
  const float* vp = v + base;
  float aq = 0.f, ak = 0.f;
  for (int i = 0; i < SEQ / 16; ++i) {
    const float w = gqw[s0 + i];
    const float qv = qp[(size_t)i * DM];
    aq += w * qv;
    ak += gkw[s0 + i] * kp[(size_t)i * DM];
    qb[base + (size_t)i * DM] = f2bf(w * qv);
    vb[base + (size_t)i * DM] = f2bf(vp[(size_t)i * DM]);
  }
  atomicAdd(&qr[b * DM + d], aq);
  atomicAdd(&kr[b * DM + d], ak);
  if (b == 0 && dch == 0 && threadIdx.x < SEQ / 16) {
    atomicAdd(&G[0], gqw[s0 + threadIdx.x]);
    atomicAdd(&G[1], gkw[s0 + threadIdx.x]);
  }
}

// K2a: partial GEMV over K-chunks
__global__ void k_gpart(const float* __restrict__ wq, const float* __restrict__ wk,
                        const float* __restrict__ qr, const float* __restrict__ kr,
                        float* __restrict__ qacc, float* __restrict__ kacc) {
  const int d = blockIdx.x * 256 + threadIdx.x;
  const int k0 = blockIdx.y * 32;
  __shared__ float sq[4][32], sk[4][32];
  if (threadIdx.x < 128) {
    const int b = threadIdx.x >> 5, kk = threadIdx.x & 31;
    sq[b][kk] = qr[b * DM + k0 + kk];
    sk[b][kk] = kr[b * DM + k0 + kk];
  }
  __syncthreads();
  float aq[4] = {0.f, 0.f, 0.f, 0.f}, ak[4] = {0.f, 0.f, 0.f, 0.f};
#pragma unroll 8
  for (int kk = 0; kk < 32; ++kk) {
    const float wqv = wq[(size_t)(k0 + kk) * DM + d];
    const float wkv = wk[(size_t)(k0 + kk) * DM + d];
#pragma unroll
    for (int b = 0; b < 4; ++b) {
      aq[b] += sq[b][kk] * wqv;
      ak[b] += sk[b][kk] * wkv;
    }
  }
#pragma unroll
  for (int b = 0; b < 4; ++b) {
    atomicAdd(&qacc[b * DM + d], aq[b]);
    atomicAdd(&kacc[b * DM + d], ak[b]);
  }
}

// K2b: gk[b,d] = (qacc + bq[d]*G0) * (kacc + bk[d]*G1)
__global__ void k_gfin(const float* __restrict__ qacc, const float* __restrict__ kacc,
                       const float* __restrict__ bq, const float* __restrict__ bk,
                       const float* __restrict__ G, float* __restrict__ gk) {
  const int i = blockIdx.x * 256 + threadIdx.x;
  const int d = i & (DM - 1);
  const float gqv = qacc[i] + bq[d] * G[0];
  const float gkr = kacc[i] + bk[d] * G[1];
  gk[i] = gqv * gkr;
}

// K3: fp32 -> bf16 row-major convert (y=0: wq->wqB, y=1: wv->wvB)
__global__ void k_conv(const float* __restrict__ x0, ushort_t* __restrict__ y0,
                       const float* __restrict__ x1, ushort_t* __restrict__ y1) {
  const float* x = blockIdx.y ? x1 : x0;
  ushort_t* y = blockIdx.y ? y1 : y0;
  size_t i = (size_t)blockIdx.x * 256 + threadIdx.x;
  const float4* p = (const float4*)x + i * 2;
  float4 a = p[0], b = p[1];
  u16x8 o;
  o[0] = f2bf(a.x); o[1] = f2bf(a.y); o[2] = f2bf(a.z); o[3] = f2bf(a.w);
  o[4] = f2bf(b.x); o[5] = f2bf(b.y); o[6] = f2bf(b.z); o[7] = f2bf(b.w);
  *(u16x8*)(y + i * 8) = o;
}

// K4: transpose-convert wo [K][N] fp32 -> woT [N][K] bf16
__global__ void k_trans(const float* __restrict__ W, ushort_t* __restrict__ T) {
  __shared__ float ls[32][33];
  const int bi = blockIdx.x, bj = blockIdx.y;
#pragma unroll
  for (int p = 0; p < 4; ++p) {
    int e = threadIdx.x + p * 256;
    int r = e >> 5, c = e & 31;
    ls[r][c] = W[(size_t)(bi * 32 + r) * DM + bj * 32 + c];
  }
  __syncthreads();
#pragma unroll
  for (int p = 0; p < 4; ++p) {
    int e = threadIdx.x + p * 256;
    int r = e >> 5, c = e & 31;
    T[(size_t)(bj * 32 + r) * DM + bi * 32 + c] = f2bf(ls[c][r]);
  }
}

// K5: wogT[b][n][j] = woT[n][j] * gk[b][j]
__global__ void k_wog(const ushort_t* __restrict__ woT, const float* __restrict__ gk,
                      ushort_t* __restrict__ wogT) {
  const size_t i = (size_t)blockIdx.x * 256 + threadIdx.x;
  const size_t c = i * 8;
  const int j0 = (int)(c & (DM - 1));
  const int b = (int)(c >> 20);
  u16x8 wv = *(const u16x8*)(woT + (c & ((1u << 20) - 1)));
  const float4 g0 = *(const float4*)(gk + b * DM + j0);
  const float4 g1 = *(const float4*)(gk + b * DM + j0 + 4);
  float g[8] = {g0.x, g0.y, g0.z, g0.w, g1.x, g1.y, g1.z, g1.w};
  u16x8 o;
#pragma unroll
  for (int j = 0; j < 8; ++j) o[j] = f2bf(bf2f(wv[j]) * g[j]);
  *(u16x8*)(wogT + i * 8) = o;
}

// K6: qbias[n] = sum_j bq[j]*wo[j,n];  vbias[b][n] = sum_j bv[j]*gk[b][j]*wo[j,n]
__global__ void k_bias(const float* __restrict__ wo, const float* __restrict__ bq,
                       const float* __restrict__ bv, const float* __restrict__ gk,
                       float* __restrict__ qbias, float* __restrict__ vbias) {
  const int n = blockIdx.x * 256 + threadIdx.x;
  const int k0 = blockIdx.y * 32;
  float aq = 0.f, av[4] = {0.f, 0.f, 0.f, 0.f};
  for (int kk = 0; kk < 32; ++kk) {
    const float w = wo[(size_t)(k0 + kk) * DM + n];
    aq += bq[k0 + kk] * w;
    const float bw = bv[k0 + kk] * w;
#pragma unroll
    for (int b = 0; b < 4; ++b) av[b] += bw * gk[b * DM + k0 + kk];
  }
  atomicAdd(&qbias[n], aq);
#pragma unroll
  for (int b = 0; b < 4; ++b) atomicAdd(&vbias[b * DM + n], av[b]);
}

// ---------------------------------------------------------------------------
// K7: small weight GEMMs, 128x64 tile, BK=32, 3-buf 2-deep prefetch, swizzled.
// z=0: WqoT[n,k] = sum_j woT[n,j]*wq[k,j];  z>0: WvbT[b] likewise with wogT/wv.
__global__ void k_small(const ushort_t* __restrict__ woT, const ushort_t* __restrict__ wogT,
                        const ushort_t* __restrict__ wqB, const ushort_t* __restrict__ wvB,
                        ushort_t* __restrict__ WqoT, ushort_t* __restrict__ WvbT) {
  __shared__ __align__(16) ushort_t lsA[3][128 * 32];
  __shared__ __align__(16) ushort_t lsB[3][64 * 32];
  const int z = blockIdx.z;
  const ushort_t* A  = z == 0 ? woT : wogT + (size_t)(z - 1) * (DM * DM);
  const ushort_t* Bt = z == 0 ? wqB : wvB;
  ushort_t* Out      = z == 0 ? WqoT : WvbT + (size_t)(z - 1) * (DM * DM);

  const int tid = threadIdx.x;
  const int w = tid >> 6, lane = tid & 63;
  const int m0 = blockIdx.x * 128, n0 = blockIdx.y * 64;
  const int wr = w >> 1, wc = w & 1;
  // staging: A 8 chunks (wave w: 2w, 2w+1), B 4 chunks (wave w: w)
  const int c0 = w * 2, c1 = c0 + 1;
  const int eA0 = c0 * 64 + lane, eA1 = c1 * 64 + lane, eB = w * 64 + lane;
  const ushort_t* gA0 = A + src_off(m0, eA0);
  const ushort_t* gA1 = A + src_off(m0, eA1);
  const ushort_t* gB0 = Bt + src_off(n0, eB);

  int aoff[4], boff[2];
#pragma unroll
  for (int i = 0; i < 4; ++i) {
    const int r = wr * 64 + i * 16 + (lane & 15);
    aoff[i] = r * 32 + (((lane >> 4) ^ ((r >> 1) & 3)) * 8);
  }
#pragma unroll
  for (int j = 0; j < 2; ++j) {
    const int r = wc * 32 + j * 16 + (lane & 15);
    boff[j] = r * 32 + (((lane >> 4) ^ ((r >> 1) & 3)) * 8);
  }

  f32x4 acc[4][2];
#pragma unroll
  for (int i = 0; i < 4; ++i)
#pragma unroll
    for (int j = 0; j < 2; ++j) acc[i][j] = (f32x4){0.f, 0.f, 0.f, 0.f};

  auto STAGE = [&](int tt, int buf) {
    const int o = tt * 32;
    GLL(gA0 + o, &lsA[buf][c0 * 512]);
    GLL(gA1 + o, &lsA[buf][c1 * 512]);
    GLL(gB0 + o, &lsB[buf][w * 512]);
  };

  STAGE(0, 0);
  STAGE(1, 1);
#pragma unroll 1
  for (int t = 0; t < 32; ++t) {
    if (t < 31) { asm volatile("s_waitcnt vmcnt(3)" ::: "memory"); }
    else        { asm volatile("s_waitcnt vmcnt(0)" ::: "memory"); }
    __builtin_amdgcn_s_barrier();
    if (t + 2 < 32) STAGE(t + 2, (t + 2) % 3);
    const int cur = t % 3;
    bf16x8 av[4], bv[2];
#pragma unroll
    for (int i = 0; i < 4; ++i) av[i] = *(const bf16x8*)(&lsA[cur][aoff[i]]);
#pragma unroll
    for (int j = 0; j < 2; ++j) bv[j] = *(const bf16x8*)(&lsB[cur][boff[j]]);
#pragma unroll
    for (int i = 0; i < 4; ++i)
#pragma unroll
      for (int j = 0; j < 2; ++j)
        acc[i][j] = __builtin_amdgcn_mfma_f32_16x16x32_bf16(av[i], bv[j], acc[i][j], 0, 0, 0);
  }

  const int lr = (lane >> 4) * 4, lc = lane & 15;
  const int rbase = m0 + wr * 64, cbase = n0 + wc * 32;
#pragma unroll
  for (int j = 0; j < 2; ++j) {
    const int col = cbase + j * 16 + lc;
#pragma unroll
    for (int i = 0; i < 4; ++i)
#pragma unroll
      for (int t = 0; t < 4; ++t)
        Out[(size_t)(rbase + i * 16 + lr + t) * DM + col] = f2bf(acc[i][j][t]);
  }
}

// ---------------------------------------------------------------------------
// K8: the big GEMM, 128x64 tile, K_eff=2048 (q-side tiles 0..31, v-side 32..63),
// 3-buf 2-deep prefetch, swizzled. 1024 blocks (4/CU).
__global__ void k_big(const ushort_t* __restrict__ qb, const ushort_t* __restrict__ vb,
                      const ushort_t* __restrict__ WqoT, const ushort_t* __restrict__ WvbT,
                      const float* __restrict__ gqw, const float* __restrict__ qbias,
                      const float* __restrict__ vbias, const float* __restrict__ bo,
                      float* __restrict__ Out) {
  __shared__ __align__(16) ushort_t lsA[3][128 * 32];
  __shared__ __align__(16) ushort_t lsB[3][64 * 32];
  const int tid = threadIdx.x;
  const int w = tid >> 6, lane = tid & 63;
  const int m0 = blockIdx.x * 128, n0 = blockIdx.y * 64;
  const int b = m0 >> 11;
  const int wr = w >> 1, wc = w & 1;
  const int c0 = w * 2, c1 = c0 + 1;
  const int eA0 = c0 * 64 + lane, eA1 = c1 * 64 + lane, eB = w * 64 + lane;
  const size_t oA0 = src_off(m0, eA0), oA1 = src_off(m0, eA1), oB = src_off(n0, eB);
  const ushort_t* gAq0 = qb + oA0;
  const ushort_t* gAq1 = qb + oA1;
  const ushort_t* gAv0 = vb + oA0;
  const ushort_t* gAv1 = vb + oA1;
  const ushort_t* gBq0 = WqoT + oB;
  const ushort_t* gBv0 = WvbT + (size_t)b * (DM * DM) + oB;

  int aoff[4], boff[2];
#pragma unroll
  for (int i = 0; i < 4; ++i) {
    const int r = wr * 64 + i * 16 + (lane & 15);
    aoff[i] = r * 32 + (((lane >> 4) ^ ((r >> 1) & 3)) * 8);
  }
#pragma unroll
  for (int j = 0; j < 2; ++j) {
    const int r = wc * 32 + j * 16 + (lane & 15);
    boff[j] = r * 32 + (((lane >> 4) ^ ((r >> 1) & 3)) * 8);
  }

  f32x4 acc[4][2];
#pragma unroll
  for (int i = 0; i < 4; ++i)
#pragma unroll
    for (int j = 0; j < 2; ++j) acc[i][j] = (f32x4){0.f, 0.f, 0.f, 0.f};

  auto STAGE = [&](int tt, int buf) {
    const ushort_t *a0, *a1, *bb;
    if (tt < 32) {
      const int o = tt * 32;
      a0 = gAq0 + o; a1 = gAq1 + o; bb = gBq0 + o;
    } else {
      const int o = (tt - 32) * 32;
      a0 = gAv0 + o; a1 = gAv1 + o; bb = gBv0 + o;
    }
    GLL(a0, &lsA[buf][c0 * 512]);
    GLL(a1, &lsA[buf][c1 * 512]);
    GLL(bb, &lsB[buf][w * 512]);
  };

  STAGE(0, 0);
  STAGE(1, 1);
#pragma unroll 1
  for (int t = 0; t < 64; ++t) {
    if (t < 63) { asm volatile("s_waitcnt vmcnt(3)" ::: "memory"); }
    else        { asm volatile("s_waitcnt vmcnt(0)" ::: "memory"); }
    __builtin_amdgcn_s_barrier();
    if (t + 2 < 64) STAGE(t + 2, (t + 2) % 3);
    const int cur = t % 3;
    bf16x8 av[4], bv[2];
#pragma unroll
    for (int i = 0; i < 4; ++i) av[i] = *(const bf16x8*)(&lsA[cur][aoff[i]]);
#pragma unroll
    for (int j = 0; j < 2; ++j) bv[j] = *(const bf16x8*)(&lsB[cur][boff[j]]);
#pragma unroll
    for (int i = 0; i < 4; ++i)
#pragma unroll
      for (int j = 0; j < 2; ++j)
        acc[i][j] = __builtin_amdgcn_mfma_f32_16x16x32_bf16(av[i], bv[j], acc[i][j], 0, 0, 0);
  }

  const int lr = (lane >> 4) * 4, lc = lane & 15;
  const int rbase = m0 + wr * 64, cbase = n0 + wc * 32;
#pragma unroll
  for (int j = 0; j < 2; ++j) {
    const int col = cbase + j * 16 + lc;
    const float qbn = qbias[col];
    const float cb = vbias[b * DM + col] + bo[col];
#pragma unroll
    for (int i = 0; i < 4; ++i)
#pragma unroll
      for (int t = 0; t < 4; ++t) {
        const int row = rbase + i * 16 + lr + t;
        Out[(size_t)row * DM + col] = acc[i][j][t] + gqw[row & (SEQ - 1)] * qbn + cb;
      }
  }
}

// ---------------------------------------------------------------------------
extern "C" void kernel_launch(void* const* d_in, const int* in_sizes, int n_in,
                              void* d_out, int out_size, void* d_ws, size_t ws_size,
                              hipStream_t stream) {
  // input order: v k q mask wq bq wk bk wv bv gqw gkw wo bo
  const float* v   = (const float*)d_in[0];
  const float* k   = (const float*)d_in[1];
  const float* q   = (const float*)d_in[2];
  const float* wq  = (const float*)d_in[4];
  const float* bq  = (const float*)d_in[5];
  const float* wk  = (const float*)d_in[6];
  const float* bk  = (const float*)d_in[7];
  const float* wv  = (const float*)d_in[8];
  const float* bv  = (const float*)d_in[9];
  const float* gqw = (const float*)d_in[10];
  const float* gkw = (const float*)d_in[11];
  const float* wo  = (const float*)d_in[12];
  const float* bo  = (const float*)d_in[13];
  float* out = (float*)d_out;
  float* wsf = (float*)d_ws;

  // fp32 scratch: [qr kr qacc kacc | G | qbias | vbias | gk]
  float* qr    = wsf + 0;
  float* kr    = wsf + 4096;
  float* qacc  = wsf + 8192;
  float* kacc  = wsf + 12288;
  float* G     = wsf + 16384;   // 2 floats
  float* qbias = wsf + 16640;   // 1024
  float* vbias = wsf + 17664;   // 4096
  float* gk    = wsf + 21760;   // 4096 (fully written by k_gfin)
  // bf16 scratch at byte offset 128 KiB
  ushort_t* b16  = (ushort_t*)((char*)d_ws + (1 << 17));
  ushort_t* qb   = b16;                                 // 16MB gqw-scaled
  ushort_t* vb   = qb + (size_t)M_TOT * DM;             // 16MB
  ushort_t* wqB  = vb + (size_t)M_TOT * DM;             // 2MB
  ushort_t* wvB  = wqB + (size_t)DM * DM;               // 2MB
  ushort_t* woT  = wvB + (size_t)DM * DM;               // 2MB [N][K]
  ushort_t* WqoT = woT + (size_t)DM * DM;               // 2MB
  ushort_t* WvbT = WqoT + (size_t)DM * DM;              // 8MB [4][N][K]
  ushort_t* wogT = (ushort_t*)out;  // 8MB alias in d_out; dead before k_big writes

  hipMemsetAsync(d_ws, 0, 21760 * sizeof(float), stream);

  // weight preps
  k_conv<<<dim3((DM * DM / 8) / 256, 2), 256, 0, stream>>>(wq, wqB, wv, wvB);
  k_trans<<<dim3(32, 32), 256, 0, stream>>>(wo, woT);

  // data reductions + bf16 conversions
  k_reduce<<<dim3(BATCH, DM / 256, 16), 256, 0, stream>>>(q, k, v, gqw, gkw, qr, kr, G, qb, vb);

  // gk
  k_gpart<<<dim3(DM / 256, DM / 32), 256, 0, stream>>>(wq, wk, qr, kr, qacc, kacc);
  k_gfin<<<(BATCH * DM) / 256, 256, 0, stream>>>(qacc, kacc, bq, bk, G, gk);

  // composed-weight preps
  k_wog<<<(BATCH * DM * DM / 8) / 256, 256, 0, stream>>>(woT, gk, wogT);
  k_bias<<<dim3(DM / 256, DM / 32), 256, 0, stream>>>(wo, bq, bv, gk, qbias, vbias);

  // small GEMMs: WqoT, WvbT[0..3]
  k_small<<<dim3(8, 16, 5), 256, 0, stream>>>(woT, wogT, wqB, wvB, WqoT, WvbT);

  // the one big GEMM -> out
  k_big<<<dim3(M_TOT / 128, DM / 64), 256, 0, stream>>>(
      qb, vb, WqoT, WvbT, gqw, qbias, vbias, bo, out);
}